// Round 2
// baseline (1398.693 us; speedup 1.0000x reference)
//
#include <hip/hip_runtime.h>

#define BB 8
#define SS 4096
#define DDIM 1024
#define FDIM 3072
#define CHUNK 128
#define NCH (SS/CHUNK)      // 32 chunks per sequence

typedef __attribute__((ext_vector_type(8))) __bf16 bf16x8;
typedef __attribute__((ext_vector_type(4))) float f32x4;

__device__ __forceinline__ unsigned short f2bf(float f) {
  unsigned int u = __builtin_bit_cast(unsigned int, f);
  u += 0x7FFFu + ((u >> 16) & 1u);          // round-to-nearest-even
  return (unsigned short)(u >> 16);
}
__device__ __forceinline__ float sigmoid_(float x) { return 1.0f / (1.0f + __expf(-x)); }
__device__ __forceinline__ float tanh_(float x) {
  float xc = fminf(fmaxf(x, -15.0f), 15.0f);
  float e = __expf(2.0f * xc);
  return (e - 1.0f) / (e + 1.0f);
}

// ---------------- weight transpose + bf16 pack ----------------
// dst[n'][Kd] = bf16(src[k][c]), where src is [K][C] row-major.
// mode 0: n' = c + rowoff                               (plain transpose)
// mode 1: n' = ((c>>5)<<6) + (c&31)                     (swiglu gate cols)
// mode 2: n' = ((c>>5)<<6) + 32 + (c&31)                (swiglu up cols)
// mode 3/4/5: n' = ((c>>4)<<6) + (mode-3)*16 + (c&15)   (g/v/d 16-col planes)
//             mode 5 additionally zeros plane 3 (n'+16)
__global__ __launch_bounds__(256)
void pack_w(const float* __restrict__ src, unsigned short* __restrict__ dst,
            int Csrc, int Kd, int mode, int rowoff)
{
  __shared__ float tile[64][65];
  const int k0 = blockIdx.y << 6;
  const int c0 = blockIdx.x << 6;
  const int t  = threadIdx.x;
  const int tc = t & 63;
  const int tr = t >> 6;
#pragma unroll
  for (int j = 0; j < 16; j++) {
    int r = (j << 2) + tr;
    tile[r][tc] = src[(size_t)(k0 + r) * Csrc + c0 + tc];
  }
  __syncthreads();
#pragma unroll
  for (int j = 0; j < 16; j++) {
    int c  = (j << 2) + tr;
    int gc = c0 + c;
    int np;
    if (mode == 0)      np = gc + rowoff;
    else if (mode == 1) np = ((gc >> 5) << 6) + (gc & 31);
    else if (mode == 2) np = ((gc >> 5) << 6) + 32 + (gc & 31);
    else                np = ((gc >> 4) << 6) + ((mode - 3) << 4) + (gc & 15);
    dst[(size_t)np * Kd + k0 + tc] = f2bf(tile[tc][c]);
    if (mode == 5) dst[(size_t)(np + 16) * Kd + k0 + tc] = 0;   // zero plane 3
  }
}

__global__ void pack_bias(const float* __restrict__ bg, const float* __restrict__ bv,
                          const float* __restrict__ bd, float* __restrict__ bias)
{
  int i = blockIdx.x * 256 + threadIdx.x;
  if (i < DDIM) { bias[i] = bg[i]; bias[i + DDIM] = bv[i]; bias[i + 2 * DDIM] = bd[i]; }
}

// ---------------- RMSNorm: fp32 in -> bf16 out ----------------
__global__ __launch_bounds__(256)
void rmsnorm_kernel(const float* __restrict__ x, const float* __restrict__ w,
                    unsigned short* __restrict__ out)
{
  const int row = blockIdx.x;
  const int t = threadIdx.x;
  const float4 v = reinterpret_cast<const float4*>(x + (size_t)row * DDIM)[t];
  float ss = v.x * v.x + v.y * v.y + v.z * v.z + v.w * v.w;
#pragma unroll
  for (int o = 32; o > 0; o >>= 1) ss += __shfl_down(ss, o);
  __shared__ float wsum[4];
  if ((t & 63) == 0) wsum[t >> 6] = ss;
  __syncthreads();
  float tot = wsum[0] + wsum[1] + wsum[2] + wsum[3];
  const float rms = rsqrtf(tot * (1.0f / DDIM) + 1e-6f);
  const float4 wv = reinterpret_cast<const float4*>(w)[t];
  ushort4 o4;
  o4.x = f2bf(v.x * rms * wv.x);
  o4.y = f2bf(v.y * rms * wv.y);
  o4.z = f2bf(v.z * rms * wv.z);
  o4.w = f2bf(v.w * rms * wv.w);
  reinterpret_cast<ushort4*>(out + (size_t)row * DDIM)[t] = o4;
}

// ---------------- bf16 MFMA GEMM, 128x128 tile, BK=64 ----------------
// A [M][K] bf16 row-major, Bt [Np][K] bf16 (pre-transposed weights).
// LDS tiles [128 rows][64 k], XOR-swizzled (byte ^= (row&7)<<4), filled by
// global_load_lds width=16 with pre-swizzled global source (rule #21).
// EPI 0: mixer -> a/xs:  ax[row][ch] = a, ax[row][1024+ch] = xs   (fp32)
// EPI 1: swiglu pairing: outh[row][Np/2 cols] = bf16(silu(g)*u)
// EPI 2: outf[row][col] = acc + resid[row][col]                   (fp32)
template<int EPI>
__global__ __launch_bounds__(256)
void gemm_bf16(const unsigned short* __restrict__ A,
               const unsigned short* __restrict__ Bt,
               int Np, int K,
               const float* __restrict__ bias,
               const float* __restrict__ resid,
               float* __restrict__ outf,
               unsigned short* __restrict__ outh)
{
  __shared__ __align__(16) unsigned short As[128 * 64];
  __shared__ __align__(16) unsigned short Bs[128 * 64];
  const int tid  = threadIdx.x;
  const int wid  = tid >> 6;
  const int lane = tid & 63;
  const int m0 = blockIdx.y << 7;
  const int n0 = blockIdx.x << 7;
  const int wr = wid >> 1, wc = wid & 1;

  f32x4 acc[4][4];
  const f32x4 zero = {0.f, 0.f, 0.f, 0.f};
#pragma unroll
  for (int i = 0; i < 4; i++)
#pragma unroll
    for (int j = 0; j < 4; j++) acc[i][j] = zero;

  for (int k0 = 0; k0 < K; k0 += 64) {
#pragma unroll
    for (int c = 0; c < 4; c++) {
      const int chunk = (wid << 2) + c;                 // 16 chunks of 1KiB
      const int r  = (chunk << 3) + (lane >> 3);        // row 0..127
      const int kk = ((((lane & 7) << 4) ^ ((r & 7) << 4)) >> 1); // swz k elem
      const unsigned short* ga = A  + (size_t)(m0 + r) * K + (k0 + kk);
      const unsigned short* gb = Bt + (size_t)(n0 + r) * K + (k0 + kk);
      __builtin_amdgcn_global_load_lds(
          (__attribute__((address_space(1))) void*)ga,
          (__attribute__((address_space(3))) void*)(&As[chunk << 9]), 16, 0, 0);
      __builtin_amdgcn_global_load_lds(
          (__attribute__((address_space(1))) void*)gb,
          (__attribute__((address_space(3))) void*)(&Bs[chunk << 9]), 16, 0, 0);
    }
    __syncthreads();

    bf16x8 af[2][4], bfv[2][4];
#pragma unroll
    for (int h = 0; h < 2; h++) {
      const int kb = (h << 5) + ((lane >> 4) << 3);     // k element base
#pragma unroll
      for (int i = 0; i < 4; i++) {
        const int ra = (wr << 6) + (i << 4) + (lane & 15);
        const int oa = ((ra << 7) + ((kb << 1) ^ ((ra & 7) << 4))) >> 1;
        af[h][i] = *reinterpret_cast<const bf16x8*>(&As[oa]);
        const int rb = (wc << 6) + (i << 4) + (lane & 15);
        const int ob = ((rb << 7) + ((kb << 1) ^ ((rb & 7) << 4))) >> 1;
        bfv[h][i] = *reinterpret_cast<const bf16x8*>(&Bs[ob]);
      }
    }
#pragma unroll
    for (int h = 0; h < 2; h++)
#pragma unroll
      for (int i = 0; i < 4; i++)
#pragma unroll
        for (int j = 0; j < 4; j++)
          acc[i][j] = __builtin_amdgcn_mfma_f32_16x16x32_bf16(af[h][i], bfv[h][j], acc[i][j], 0, 0, 0);
    __syncthreads();
  }

  // epilogue: C/D layout col = lane&15, row = (lane>>4)*4 + reg  [m89]
  const int lcol = lane & 15;
  const int rgrp = (lane >> 4) << 2;
  if (EPI == 0) {
    // mixer: j=0 g, j=1 v, j=2 d (plane-interleaved B), j=3 pad
    const int ch = (n0 >> 2) + (wc << 4) + lcol;        // channel 0..1023
    const float bgv = bias[ch], bvv = bias[ch + DDIM], bdv = bias[ch + 2 * DDIM];
#pragma unroll
    for (int i = 0; i < 4; i++)
#pragma unroll
      for (int rg = 0; rg < 4; rg++) {
        const int row = m0 + (wr << 6) + (i << 4) + rgrp + rg;
        const float g  = acc[i][0][rg] + bgv;
        const float v  = acc[i][1][rg] + bvv;
        const float dd = acc[i][2][rg] + bdv;
        const float a  = 0.001f + 0.998f * sigmoid_(dd);
        const float xs = sigmoid_(g) * tanh_(v);
        float* o = outf + (size_t)row * (2 * DDIM);
        o[ch] = a;
        o[ch + DDIM] = xs;
      }
  } else if (EPI == 1) {
    const int tN = Np >> 1;
#pragma unroll
    for (int i = 0; i < 4; i++)
#pragma unroll
      for (int j = 0; j < 2; j++) {
        const int tcol = (n0 >> 1) + (wc << 5) + (j << 4) + lcol;
#pragma unroll
        for (int rg = 0; rg < 4; rg++) {
          const int row = m0 + (wr << 6) + (i << 4) + rgrp + rg;
          const float g = acc[i][j][rg];
          const float u = acc[i][j + 2][rg];
          const float s = g / (1.0f + __expf(-g));      // silu
          outh[(size_t)row * tN + tcol] = f2bf(s * u);
        }
      }
  } else {
#pragma unroll
    for (int i = 0; i < 4; i++)
#pragma unroll
      for (int j = 0; j < 4; j++) {
        const int col = n0 + (wc << 6) + (j << 4) + lcol;
#pragma unroll
        for (int rg = 0; rg < 4; rg++) {
          const int row = m0 + (wr << 6) + (i << 4) + rgrp + rg;
          outf[(size_t)row * Np + col] = acc[i][j][rg] + resid[(size_t)row * Np + col];
        }
      }
  }
}

// ---------------- chunked linear scan over precomputed (a, xs) ----------------
// ax [Mg][2048] fp32: a = col d, xs = col 1024+d
__global__ __launch_bounds__(256)
void scan_phase1(const float* __restrict__ ax, float* __restrict__ Ac, float* __restrict__ Hc)
{
  const int d = blockIdx.x * 256 + threadIdx.x;
  const int ch = blockIdx.y;
  const int b = blockIdx.z;
  size_t base = ((size_t)b * SS + (size_t)ch * CHUNK) * (2 * DDIM) + d;
  float Aprod = 1.0f, H = 0.0f;
  for (int s = 0; s < CHUNK; s++) {
    const float a  = ax[base];
    const float xs = ax[base + DDIM];
    H = a * H + xs;
    Aprod *= a;
    base += 2 * DDIM;
  }
  const int idx = (b * NCH + ch) * DDIM + d;
  Ac[idx] = Aprod;
  Hc[idx] = H;
}

__global__ void scan_phase2(const float* __restrict__ Ac, const float* __restrict__ Hc,
                            float* __restrict__ Hpre)
{
  const int idx = blockIdx.x * 256 + threadIdx.x;
  const int b = idx >> 10, d = idx & (DDIM - 1);
  float h = 0.0f;
  for (int c = 0; c < NCH; c++) {
    const int i = (b * NCH + c) * DDIM + d;
    Hpre[i] = h;
    h = Ac[i] * h + Hc[i];
  }
}

__global__ __launch_bounds__(256)
void scan_phase3(const float* __restrict__ ax, const float* __restrict__ x,
                 const float* __restrict__ Hpre, float* __restrict__ xres)
{
  const int d = blockIdx.x * 256 + threadIdx.x;
  const int ch = blockIdx.y;
  const int b = blockIdx.z;
  float H = Hpre[(b * NCH + ch) * DDIM + d];
  const size_t mbase = (size_t)b * SS + (size_t)ch * CHUNK;
  size_t base  = mbase * (2 * DDIM) + d;
  size_t xbase = mbase * DDIM + d;
  for (int s = 0; s < CHUNK; s++) {
    const float a  = ax[base];
    const float xs = ax[base + DDIM];
    H = a * H + xs;
    xres[xbase] = x[xbase] + H;
    base += 2 * DDIM;
    xbase += DDIM;
  }
}

// ---------------- launch ----------------
extern "C" void kernel_launch(void* const* d_in, const int* in_sizes, int n_in,
                              void* d_out, int out_size, void* d_ws, size_t ws_size,
                              hipStream_t stream)
{
  const float* x         = (const float*)d_in[0];
  const float* w_rms_mix = (const float*)d_in[1];
  const float* w_rms_ffn = (const float*)d_in[2];
  const float* Wg  = (const float*)d_in[3];
  const float* bg  = (const float*)d_in[4];
  const float* Wv  = (const float*)d_in[5];
  const float* bv  = (const float*)d_in[6];
  const float* Wd  = (const float*)d_in[7];
  const float* bd  = (const float*)d_in[8];
  const float* Wga = (const float*)d_in[9];
  const float* Wup = (const float*)d_in[10];
  const float* Wo  = (const float*)d_in[11];
  float* out = (float*)d_out;

  // ---- workspace carve (ws-size adaptive) ----
  char* p = (char*)d_ws;
  auto carve = [&](size_t bytes) -> char* {
    char* r = p; p += (bytes + 255) & ~(size_t)255; return r;
  };
  unsigned short* Wgvd4 = (unsigned short*)carve((size_t)4 * DDIM * DDIM * 2); // 8.4 MB (4 planes: g,v,d,0)
  unsigned short* WguT  = (unsigned short*)carve((size_t)2 * FDIM * DDIM * 2); // 12.6 MB
  unsigned short* WoutT = (unsigned short*)carve((size_t)DDIM * FDIM * 2);     // 6.3 MB
  float* bias = (float*)carve(3 * DDIM * 4);
  const size_t fixed_used = (size_t)(p - (char*)d_ws);

  const size_t xn_b  = (size_t)SS * DDIM * 2;       // per batch
  const size_t ax_b  = (size_t)SS * 2 * DDIM * 4;   // per batch (tact bf16 [S][F] aliases: 25.2MB < 33.6MB)
  const size_t ach_b = (size_t)NCH * DDIM * 4;      // per batch
  const size_t per_batch = xn_b + ax_b + 3 * ach_b + 2048;
  long long avail = (long long)ws_size - (long long)fixed_used;
  int nb = (avail > 0) ? (int)(avail / (long long)per_batch) : 1;
  if (nb < 1) nb = 1;
  if (nb > BB) nb = BB;

  unsigned short* xn = (unsigned short*)carve((size_t)nb * xn_b);
  float* ax   = (float*)carve((size_t)nb * ax_b);
  unsigned short* tact = (unsigned short*)ax;       // aliases ax (dead after scan)
  float* Ac   = (float*)carve((size_t)nb * ach_b);
  float* Hc   = (float*)carve((size_t)nb * ach_b);
  float* Hpre = (float*)carve((size_t)nb * ach_b);

  // ---- pack weights once (transpose to [N][K] bf16) + bias ----
  pack_w<<<dim3(16, 16), 256, 0, stream>>>(Wg,  Wgvd4, DDIM, DDIM, 3, 0);
  pack_w<<<dim3(16, 16), 256, 0, stream>>>(Wv,  Wgvd4, DDIM, DDIM, 4, 0);
  pack_w<<<dim3(16, 16), 256, 0, stream>>>(Wd,  Wgvd4, DDIM, DDIM, 5, 0);
  pack_w<<<dim3(48, 16), 256, 0, stream>>>(Wga, WguT,  FDIM, DDIM, 1, 0);
  pack_w<<<dim3(48, 16), 256, 0, stream>>>(Wup, WguT,  FDIM, DDIM, 2, 0);
  pack_w<<<dim3(16, 48), 256, 0, stream>>>(Wo,  WoutT, DDIM, FDIM, 0, 0);
  pack_bias<<<4, 256, 0, stream>>>(bg, bv, bd, bias);

  // ---- per-batch-group pipeline ----
  for (int b0 = 0; b0 < BB; b0 += nb) {
    const int n  = (BB - b0 < nb) ? (BB - b0) : nb;
    const int Mg = n * SS;
    const float* xg   = x   + (size_t)b0 * SS * DDIM;
    float*       outg = out + (size_t)b0 * SS * DDIM;   // holds xres, then final

    // rmsnorm #1 -> xn (bf16)
    rmsnorm_kernel<<<Mg, 256, 0, stream>>>(xg, w_rms_mix, xn);

    // mixer GEMM (4-plane padded): epilogue computes (a, xs) fp32
    gemm_bf16<0><<<dim3(4 * DDIM / 128, Mg / 128), 256, 0, stream>>>(
        xn, Wgvd4, 4 * DDIM, DDIM, bias, nullptr, ax, nullptr);

    // chunked scan -> outg = x + h
    scan_phase1<<<dim3(DDIM / 256, NCH, n), 256, 0, stream>>>(ax, Ac, Hc);
    scan_phase2<<<(n * DDIM) / 256, 256, 0, stream>>>(Ac, Hc, Hpre);
    scan_phase3<<<dim3(DDIM / 256, NCH, n), 256, 0, stream>>>(ax, xg, Hpre, outg);

    // rmsnorm #2 -> yn (bf16, reuse xn)
    rmsnorm_kernel<<<Mg, 256, 0, stream>>>(outg, w_rms_ffn, xn);

    // FFN1: tact = silu(yn@Wgate) * (yn@Wup)  (bf16, fused epilogue)
    gemm_bf16<1><<<dim3(2 * FDIM / 128, Mg / 128), 256, 0, stream>>>(
        xn, WguT, 2 * FDIM, DDIM, nullptr, nullptr, nullptr, tact);

    // FFN2: outg = tact @ Wout + outg(resid)
    gemm_bf16<2><<<dim3(DDIM / 128, Mg / 128), 256, 0, stream>>>(
        tact, WoutT, DDIM, FDIM, nullptr, outg, outg, nullptr);
  }
}

// Round 3
// 1139.660 us; speedup vs baseline: 1.2273x; 1.2273x over previous
//
#include <hip/hip_runtime.h>

#define BB 8
#define SS 4096
#define DDIM 1024
#define FDIM 3072
#define CHUNK 128
#define NCH (SS/CHUNK)      // 32 chunks per sequence

typedef __attribute__((ext_vector_type(8))) __bf16 bf16x8;
typedef __attribute__((ext_vector_type(4))) float f32x4;

__device__ __forceinline__ unsigned short f2bf(float f) {
  unsigned int u = __builtin_bit_cast(unsigned int, f);
  u += 0x7FFFu + ((u >> 16) & 1u);          // round-to-nearest-even
  return (unsigned short)(u >> 16);
}
__device__ __forceinline__ float sigmoid_(float x) { return 1.0f / (1.0f + __expf(-x)); }
__device__ __forceinline__ float tanh_(float x) {
  float xc = fminf(fmaxf(x, -15.0f), 15.0f);
  float e = __expf(2.0f * xc);
  return (e - 1.0f) / (e + 1.0f);
}

// ---------------- weight transpose + bf16 pack ----------------
// dst[n'][Kd] = bf16(src[k][c]), src is [K][C] row-major.
// mode 0: n' = c + rowoff
// mode 1: n' = ((c>>5)<<6) + (c&31)                     (swiglu gate cols)
// mode 2: n' = ((c>>5)<<6) + 32 + (c&31)                (swiglu up cols)
// mode 3/4/5: n' = ((c>>4)<<6) + (mode-3)*16 + (c&15)   (g/v/d 16-col planes)
//             mode 5 additionally zeros plane 3 (n'+16)
__global__ __launch_bounds__(256)
void pack_w(const float* __restrict__ src, unsigned short* __restrict__ dst,
            int Csrc, int Kd, int mode, int rowoff)
{
  __shared__ float tile[64][65];
  const int k0 = blockIdx.y << 6;
  const int c0 = blockIdx.x << 6;
  const int t  = threadIdx.x;
  const int tc = t & 63;
  const int tr = t >> 6;
#pragma unroll
  for (int j = 0; j < 16; j++) {
    int r = (j << 2) + tr;
    tile[r][tc] = src[(size_t)(k0 + r) * Csrc + c0 + tc];
  }
  __syncthreads();
#pragma unroll
  for (int j = 0; j < 16; j++) {
    int c  = (j << 2) + tr;
    int gc = c0 + c;
    int np;
    if (mode == 0)      np = gc + rowoff;
    else if (mode == 1) np = ((gc >> 5) << 6) + (gc & 31);
    else if (mode == 2) np = ((gc >> 5) << 6) + 32 + (gc & 31);
    else                np = ((gc >> 4) << 6) + ((mode - 3) << 4) + (gc & 15);
    dst[(size_t)np * Kd + k0 + tc] = f2bf(tile[tc][c]);
    if (mode == 5) dst[(size_t)(np + 16) * Kd + k0 + tc] = 0;   // zero plane 3
  }
}

__global__ void pack_bias(const float* __restrict__ bg, const float* __restrict__ bv,
                          const float* __restrict__ bd, float* __restrict__ bias)
{
  int i = blockIdx.x * 256 + threadIdx.x;
  if (i < DDIM) { bias[i] = bg[i]; bias[i + DDIM] = bv[i]; bias[i + 2 * DDIM] = bd[i]; }
}

// ---------------- RMSNorm: fp32 in -> bf16 out ----------------
__global__ __launch_bounds__(256)
void rmsnorm_kernel(const float* __restrict__ x, const float* __restrict__ w,
                    unsigned short* __restrict__ out)
{
  const int row = blockIdx.x;
  const int t = threadIdx.x;
  const float4 v = reinterpret_cast<const float4*>(x + (size_t)row * DDIM)[t];
  float ss = v.x * v.x + v.y * v.y + v.z * v.z + v.w * v.w;
#pragma unroll
  for (int o = 32; o > 0; o >>= 1) ss += __shfl_down(ss, o);
  __shared__ float wsum[4];
  if ((t & 63) == 0) wsum[t >> 6] = ss;
  __syncthreads();
  float tot = wsum[0] + wsum[1] + wsum[2] + wsum[3];
  const float rms = rsqrtf(tot * (1.0f / DDIM) + 1e-6f);
  const float4 wv = reinterpret_cast<const float4*>(w)[t];
  ushort4 o4;
  o4.x = f2bf(v.x * rms * wv.x);
  o4.y = f2bf(v.y * rms * wv.y);
  o4.z = f2bf(v.z * rms * wv.z);
  o4.w = f2bf(v.w * rms * wv.w);
  reinterpret_cast<ushort4*>(out + (size_t)row * DDIM)[t] = o4;
}

// ---------------- 256x256 8-phase bf16 MFMA GEMM ----------------
// A [M][K] bf16 row-major, Bt [Np][K] bf16 (pre-transposed weights).
// 512 threads = 8 waves (2M x 4N), per-wave output 128x64.
// LDS 128 KiB: 2 bufs x (A 256x64 + B 256x64), XOR-swizzle byte^=(row&7)<<4
// applied via pre-swizzled global source (linear LDS dest for global_load_lds).
// B LDS rows permuted nh-major: ldsrow = nh*128 + wc*32 + o  (o = col&31).
// Schedule: 8 phases / 2 K-tiles; counted vmcnt(4) at phases 4/8 only;
// stage calendar: ph1,2 -> buf1{A-mh1,B-nh1}(t+1); ph3..6 -> buf0 units (t+2);
// ph7,8 -> buf1{A-mh0,B-nh0}(t+3). Quadrant order (mh,nh)=00,01,10,11.

template<int MH, int NH>
__device__ __forceinline__ void mfma_quad(f32x4 (&acc)[8][4], const bf16x8 (&af)[4][2],
                                          const bf16x8 (&bfr)[2][2][2])
{
#pragma unroll
  for (int mf = 0; mf < 4; mf++)
#pragma unroll
    for (int nf = 0; nf < 2; nf++)
#pragma unroll
      for (int kk = 0; kk < 2; kk++)
        acc[MH * 4 + mf][NH * 2 + nf] = __builtin_amdgcn_mfma_f32_16x16x32_bf16(
            af[mf][kk], bfr[NH][nf][kk], acc[MH * 4 + mf][NH * 2 + nf], 0, 0, 0);
}

#define PH_PRE()  do { __builtin_amdgcn_s_barrier(); \
  asm volatile("s_waitcnt lgkmcnt(0)" ::: "memory"); \
  __builtin_amdgcn_sched_barrier(0); \
  __builtin_amdgcn_s_setprio(1); } while (0)
#define PH_POST() do { __builtin_amdgcn_s_setprio(0); \
  __builtin_amdgcn_sched_barrier(0); \
  __builtin_amdgcn_s_barrier(); \
  __builtin_amdgcn_sched_barrier(0); } while (0)

template<int EPI>
__global__ __launch_bounds__(512, 2)
void gemm256(const unsigned short* __restrict__ A,
             const unsigned short* __restrict__ Bt,
             int Np, int K,
             const float* __restrict__ bias,
             const float* __restrict__ resid,
             float* __restrict__ outf,
             unsigned short* __restrict__ outh)
{
  __shared__ __align__(16) unsigned short ldsA[2][256 * 64];
  __shared__ __align__(16) unsigned short ldsB[2][256 * 64];
  const int tid = threadIdx.x, wid = tid >> 6, lane = tid & 63;

  // bijective XCD swizzle (nwg % 8 == 0 for all our grids)
  const int gx = gridDim.x;
  const int lin = blockIdx.y * gx + blockIdx.x;
  const int cpx = (gx * gridDim.y) >> 3;
  const int swz = (lin & 7) * cpx + (lin >> 3);
  const int bx = swz % gx, by = swz / gx;
  const int m0 = by << 8, n0 = bx << 8;
  const int wr = wid >> 2, wc = wid & 3;

  f32x4 acc[8][4];
  const f32x4 zero = {0.f, 0.f, 0.f, 0.f};
#pragma unroll
  for (int a = 0; a < 8; a++)
#pragma unroll
    for (int j = 0; j < 4; j++) acc[a][j] = zero;

  // staging: unit A-mh{u} = lds rows {u*64..+64} u {128+u*64..+64}
  //          unit B-nh{u} = lds rows {u*128..+128} (perm layout)
  const int swzk = (((tid & 7) ^ ((tid >> 3) & 7)) << 3);   // src k-elem pre-swizzle
  auto stA = [&](int p, int u, int t) {
#pragma unroll
    for (int r = 0; r < 2; r++) {
      const int lrow0 = (r << 7) + (u << 6);
      const int grow = m0 + lrow0 + (tid >> 3);
      const unsigned short* src = A + (size_t)grow * K + (t << 6) + swzk;
      unsigned short* dst = &ldsA[p][lrow0 << 6] + (wid << 9);  // wave-uniform
      __builtin_amdgcn_global_load_lds(
          (const __attribute__((address_space(1))) void*)src,
          (__attribute__((address_space(3))) void*)dst, 16, 0, 0);
    }
  };
  auto stB = [&](int p, int u, int t) {
#pragma unroll
    for (int r = 0; r < 2; r++) {
      const int j = (r << 6) + (tid >> 3);
      const int lrow0 = (u << 7) + (r << 6);
      const int gcol = n0 + ((j >> 5) << 6) + (u << 5) + (j & 31);
      const unsigned short* src = Bt + (size_t)gcol * K + (t << 6) + swzk;
      unsigned short* dst = &ldsB[p][lrow0 << 6] + (wid << 9);
      __builtin_amdgcn_global_load_lds(
          (const __attribute__((address_space(1))) void*)src,
          (__attribute__((address_space(3))) void*)dst, 16, 0, 0);
    }
  };

  bf16x8 af[4][2];
  bf16x8 bfr[2][2][2];
  auto rdA = [&](const unsigned short* base, int mh) {
#pragma unroll
    for (int mf = 0; mf < 4; mf++) {
      const int row = (wr << 7) + (mh << 6) + (mf << 4) + (lane & 15);
#pragma unroll
      for (int kk = 0; kk < 2; kk++) {
        const int keb = (((kk << 6) + ((lane >> 4) << 4)) ^ ((lane & 7) << 4));
        af[mf][kk] = *reinterpret_cast<const bf16x8*>(
            reinterpret_cast<const char*>(base) + (row << 7) + keb);
      }
    }
  };
  auto rdB = [&](const unsigned short* base, bf16x8 (&dst)[2][2], int nh) {
#pragma unroll
    for (int nf = 0; nf < 2; nf++) {
      const int row = (nh << 7) + (wc << 5) + (nf << 4) + (lane & 15);
#pragma unroll
      for (int kk = 0; kk < 2; kk++) {
        const int keb = (((kk << 6) + ((lane >> 4) << 4)) ^ ((lane & 7) << 4));
        dst[nf][kk] = *reinterpret_cast<const bf16x8*>(
            reinterpret_cast<const char*>(base) + (row << 7) + keb);
      }
    }
  };

  const int NITER = (K >> 6) >> 1;   // 2 K-tiles per iter

  // ---- prologue: tile0 all 4 units -> buf0; tile1 {A-mh0,B-nh0} -> buf1 ----
  stA(0, 0, 0); stA(0, 1, 0); stB(0, 0, 0); stB(0, 1, 0);
  stA(1, 0, 1); stB(1, 0, 1);
  asm volatile("s_waitcnt vmcnt(4)" ::: "memory");   // tile0 complete
  __builtin_amdgcn_s_barrier();
  __builtin_amdgcn_sched_barrier(0);

  for (int i = 0; i < NITER; i++) {
    const int t2 = i << 1;
    const bool more = (i + 1 < NITER);
    // ---- ph1: quad(0,0) tile t2 (buf0) ----
    rdA(ldsA[0], 0);
    rdB(ldsB[0], bfr[0], 0);
    stA(1, 1, t2 + 1);
    PH_PRE();
    mfma_quad<0, 0>(acc, af, bfr);
    PH_POST();
    // ---- ph2: quad(0,1) ----
    rdB(ldsB[0], bfr[1], 1);
    stB(1, 1, t2 + 1);
    PH_PRE();
    mfma_quad<0, 1>(acc, af, bfr);
    PH_POST();
    // ---- ph3: quad(1,0) ----
    rdA(ldsA[0], 1);
    if (more) stA(0, 0, t2 + 2);
    PH_PRE();
    mfma_quad<1, 0>(acc, af, bfr);
    PH_POST();
    // ---- ph4: quad(1,1) + vmcnt ----
    if (more) stB(0, 0, t2 + 2);
    PH_PRE();
    mfma_quad<1, 1>(acc, af, bfr);
    __builtin_amdgcn_s_setprio(0);
    __builtin_amdgcn_sched_barrier(0);
    if (more) { asm volatile("s_waitcnt vmcnt(4)" ::: "memory"); }
    else      { asm volatile("s_waitcnt vmcnt(0)" ::: "memory"); }
    __builtin_amdgcn_s_barrier();
    __builtin_amdgcn_sched_barrier(0);
    // ---- ph5: quad(0,0) tile t2+1 (buf1) ----
    rdA(ldsA[1], 0);
    rdB(ldsB[1], bfr[0], 0);
    if (more) stA(0, 1, t2 + 2);
    PH_PRE();
    mfma_quad<0, 0>(acc, af, bfr);
    PH_POST();
    // ---- ph6: quad(0,1) ----
    rdB(ldsB[1], bfr[1], 1);
    if (more) stB(0, 1, t2 + 2);
    PH_PRE();
    mfma_quad<0, 1>(acc, af, bfr);
    PH_POST();
    // ---- ph7: quad(1,0) ----
    rdA(ldsA[1], 1);
    if (more) stA(1, 0, t2 + 3);
    PH_PRE();
    mfma_quad<1, 0>(acc, af, bfr);
    PH_POST();
    // ---- ph8: quad(1,1) + vmcnt ----
    if (more) stB(1, 0, t2 + 3);
    PH_PRE();
    mfma_quad<1, 1>(acc, af, bfr);
    __builtin_amdgcn_s_setprio(0);
    __builtin_amdgcn_sched_barrier(0);
    if (more) { asm volatile("s_waitcnt vmcnt(4)" ::: "memory"); }
    __builtin_amdgcn_s_barrier();
    __builtin_amdgcn_sched_barrier(0);
  }

  // ---- epilogue: C/D layout col=lane&15, row=(lane>>4)*4+reg [m89] ----
  // acc[a][j]: row = m0 + wr*128 + a*16 + (lane>>4)*4 + rg; col = n0 + wc*64 + j*16 + (lane&15)
  const int lcol = lane & 15;
  const int rgrp = (lane >> 4) << 2;
  if (EPI == 0) {
    // mixer: j=0 g, j=1 v, j=2 d (plane-interleaved B), j=3 pad
    const int ch = (n0 >> 2) + (wc << 4) + lcol;        // channel 0..1023
    const float bgv = bias[ch], bvv = bias[ch + DDIM], bdv = bias[ch + 2 * DDIM];
#pragma unroll
    for (int a = 0; a < 8; a++)
#pragma unroll
      for (int rg = 0; rg < 4; rg++) {
        const int row = m0 + (wr << 7) + (a << 4) + rgrp + rg;
        const float g  = acc[a][0][rg] + bgv;
        const float v  = acc[a][1][rg] + bvv;
        const float dd = acc[a][2][rg] + bdv;
        const float aa = 0.001f + 0.998f * sigmoid_(dd);
        const float xs = sigmoid_(g) * tanh_(v);
        float* o = outf + (size_t)row * (2 * DDIM);
        o[ch] = aa;
        o[ch + DDIM] = xs;
      }
  } else if (EPI == 1) {
    const int tN = Np >> 1;
#pragma unroll
    for (int a = 0; a < 8; a++)
#pragma unroll
      for (int j = 0; j < 2; j++) {
        const int tcol = (n0 >> 1) + (wc << 5) + (j << 4) + lcol;
#pragma unroll
        for (int rg = 0; rg < 4; rg++) {
          const int row = m0 + (wr << 7) + (a << 4) + rgrp + rg;
          const float g = acc[a][j][rg];
          const float u = acc[a][j + 2][rg];
          const float s = g / (1.0f + __expf(-g));      // silu
          outh[(size_t)row * tN + tcol] = f2bf(s * u);
        }
      }
  } else {
#pragma unroll
    for (int a = 0; a < 8; a++)
#pragma unroll
      for (int j = 0; j < 4; j++) {
        const int col = n0 + (wc << 6) + (j << 4) + lcol;
#pragma unroll
        for (int rg = 0; rg < 4; rg++) {
          const int row = m0 + (wr << 7) + (a << 4) + rgrp + rg;
          outf[(size_t)row * Np + col] = acc[a][j][rg] + resid[(size_t)row * Np + col];
        }
      }
  }
}

// ---------------- chunked linear scan over precomputed (a, xs) ----------------
__global__ __launch_bounds__(256)
void scan_phase1(const float* __restrict__ ax, float* __restrict__ Ac, float* __restrict__ Hc)
{
  const int d = blockIdx.x * 256 + threadIdx.x;
  const int ch = blockIdx.y;
  const int b = blockIdx.z;
  size_t base = ((size_t)b * SS + (size_t)ch * CHUNK) * (2 * DDIM) + d;
  float Aprod = 1.0f, H = 0.0f;
  for (int s = 0; s < CHUNK; s++) {
    const float a  = ax[base];
    const float xs = ax[base + DDIM];
    H = a * H + xs;
    Aprod *= a;
    base += 2 * DDIM;
  }
  const int idx = (b * NCH + ch) * DDIM + d;
  Ac[idx] = Aprod;
  Hc[idx] = H;
}

__global__ void scan_phase2(const float* __restrict__ Ac, const float* __restrict__ Hc,
                            float* __restrict__ Hpre)
{
  const int idx = blockIdx.x * 256 + threadIdx.x;
  const int b = idx >> 10, d = idx & (DDIM - 1);
  float h = 0.0f;
  for (int c = 0; c < NCH; c++) {
    const int i = (b * NCH + c) * DDIM + d;
    Hpre[i] = h;
    h = Ac[i] * h + Hc[i];
  }
}

__global__ __launch_bounds__(256)
void scan_phase3(const float* __restrict__ ax, const float* __restrict__ x,
                 const float* __restrict__ Hpre, float* __restrict__ xres)
{
  const int d = blockIdx.x * 256 + threadIdx.x;
  const int ch = blockIdx.y;
  const int b = blockIdx.z;
  float H = Hpre[(b * NCH + ch) * DDIM + d];
  const size_t mbase = (size_t)b * SS + (size_t)ch * CHUNK;
  size_t base  = mbase * (2 * DDIM) + d;
  size_t xbase = mbase * DDIM + d;
  for (int s = 0; s < CHUNK; s++) {
    const float a  = ax[base];
    const float xs = ax[base + DDIM];
    H = a * H + xs;
    xres[xbase] = x[xbase] + H;
    base += 2 * DDIM;
    xbase += DDIM;
  }
}

// ---------------- launch ----------------
extern "C" void kernel_launch(void* const* d_in, const int* in_sizes, int n_in,
                              void* d_out, int out_size, void* d_ws, size_t ws_size,
                              hipStream_t stream)
{
  const float* x         = (const float*)d_in[0];
  const float* w_rms_mix = (const float*)d_in[1];
  const float* w_rms_ffn = (const float*)d_in[2];
  const float* Wg  = (const float*)d_in[3];
  const float* bg  = (const float*)d_in[4];
  const float* Wv  = (const float*)d_in[5];
  const float* bv  = (const float*)d_in[6];
  const float* Wd  = (const float*)d_in[7];
  const float* bd  = (const float*)d_in[8];
  const float* Wga = (const float*)d_in[9];
  const float* Wup = (const float*)d_in[10];
  const float* Wo  = (const float*)d_in[11];
  float* out = (float*)d_out;

  // ---- workspace carve (ws-size adaptive) ----
  char* p = (char*)d_ws;
  auto carve = [&](size_t bytes) -> char* {
    char* r = p; p += (bytes + 255) & ~(size_t)255; return r;
  };
  unsigned short* Wgvd4 = (unsigned short*)carve((size_t)4 * DDIM * DDIM * 2);
  unsigned short* WguT  = (unsigned short*)carve((size_t)2 * FDIM * DDIM * 2);
  unsigned short* WoutT = (unsigned short*)carve((size_t)DDIM * FDIM * 2);
  float* bias = (float*)carve(3 * DDIM * 4);
  const size_t fixed_used = (size_t)(p - (char*)d_ws);

  const size_t xn_b  = (size_t)SS * DDIM * 2;
  const size_t ax_b  = (size_t)SS * 2 * DDIM * 4;
  const size_t ach_b = (size_t)NCH * DDIM * 4;
  const size_t per_batch = xn_b + ax_b + 3 * ach_b + 2048;
  long long avail = (long long)ws_size - (long long)fixed_used;
  int nb = (avail > 0) ? (int)(avail / (long long)per_batch) : 1;
  if (nb < 1) nb = 1;
  if (nb > BB) nb = BB;

  unsigned short* xn = (unsigned short*)carve((size_t)nb * xn_b);
  float* ax   = (float*)carve((size_t)nb * ax_b);
  unsigned short* tact = (unsigned short*)ax;       // aliases ax (dead after scan)
  float* Ac   = (float*)carve((size_t)nb * ach_b);
  float* Hc   = (float*)carve((size_t)nb * ach_b);
  float* Hpre = (float*)carve((size_t)nb * ach_b);

  // ---- pack weights once + bias ----
  pack_w<<<dim3(16, 16), 256, 0, stream>>>(Wg,  Wgvd4, DDIM, DDIM, 3, 0);
  pack_w<<<dim3(16, 16), 256, 0, stream>>>(Wv,  Wgvd4, DDIM, DDIM, 4, 0);
  pack_w<<<dim3(16, 16), 256, 0, stream>>>(Wd,  Wgvd4, DDIM, DDIM, 5, 0);
  pack_w<<<dim3(48, 16), 256, 0, stream>>>(Wga, WguT,  FDIM, DDIM, 1, 0);
  pack_w<<<dim3(48, 16), 256, 0, stream>>>(Wup, WguT,  FDIM, DDIM, 2, 0);
  pack_w<<<dim3(16, 48), 256, 0, stream>>>(Wo,  WoutT, DDIM, FDIM, 0, 0);
  pack_bias<<<4, 256, 0, stream>>>(bg, bv, bd, bias);

  // ---- per-batch-group pipeline ----
  for (int b0 = 0; b0 < BB; b0 += nb) {
    const int n  = (BB - b0 < nb) ? (BB - b0) : nb;
    const int Mg = n * SS;
    const float* xg   = x   + (size_t)b0 * SS * DDIM;
    float*       outg = out + (size_t)b0 * SS * DDIM;

    // rmsnorm #1 -> xn (bf16)
    rmsnorm_kernel<<<Mg, 256, 0, stream>>>(xg, w_rms_mix, xn);

    // mixer GEMM (4-plane padded): epilogue computes (a, xs) fp32
    gemm256<0><<<dim3(4 * DDIM / 256, Mg / 256), 512, 0, stream>>>(
        xn, Wgvd4, 4 * DDIM, DDIM, bias, nullptr, ax, nullptr);

    // chunked scan -> outg = x + h
    scan_phase1<<<dim3(DDIM / 256, NCH, n), 256, 0, stream>>>(ax, Ac, Hc);
    scan_phase2<<<(n * DDIM) / 256, 256, 0, stream>>>(Ac, Hc, Hpre);
    scan_phase3<<<dim3(DDIM / 256, NCH, n), 256, 0, stream>>>(ax, xg, Hpre, outg);

    // rmsnorm #2 -> yn (bf16, reuse xn)
    rmsnorm_kernel<<<Mg, 256, 0, stream>>>(outg, w_rms_ffn, xn);

    // FFN1: tact = silu(yn@Wgate) * (yn@Wup)  (bf16, fused epilogue)
    gemm256<1><<<dim3(2 * FDIM / 256, Mg / 256), 512, 0, stream>>>(
        xn, WguT, 2 * FDIM, DDIM, nullptr, nullptr, nullptr, tact);

    // FFN2: outg = tact @ Wout + outg(resid)
    gemm256<2><<<dim3(DDIM / 256, Mg / 256), 512, 0, stream>>>(
        tact, WoutT, DDIM, FDIM, nullptr, outg, outg, nullptr);
  }
}

// Round 4
// 1054.391 us; speedup vs baseline: 1.3265x; 1.0809x over previous
//
#include <hip/hip_runtime.h>

#define BB 8
#define SS 4096
#define DDIM 1024
#define FDIM 3072
#define CHUNK 128
#define NCH (SS/CHUNK)      // 32 chunks per sequence

typedef __attribute__((ext_vector_type(8))) __bf16 bf16x8;
typedef __attribute__((ext_vector_type(4))) float f32x4;

__device__ __forceinline__ unsigned short f2bf(float f) {
  unsigned int u = __builtin_bit_cast(unsigned int, f);
  u += 0x7FFFu + ((u >> 16) & 1u);          // round-to-nearest-even
  return (unsigned short)(u >> 16);
}
__device__ __forceinline__ float sigmoid_(float x) { return 1.0f / (1.0f + __expf(-x)); }
__device__ __forceinline__ float tanh_(float x) {
  float xc = fminf(fmaxf(x, -15.0f), 15.0f);
  float e = __expf(2.0f * xc);
  return (e - 1.0f) / (e + 1.0f);
}

// ---------------- weight transpose + bf16 pack ----------------
__global__ __launch_bounds__(256)
void pack_w(const float* __restrict__ src, unsigned short* __restrict__ dst,
            int Csrc, int Kd, int mode, int rowoff)
{
  __shared__ float tile[64][65];
  const int k0 = blockIdx.y << 6;
  const int c0 = blockIdx.x << 6;
  const int t  = threadIdx.x;
  const int tc = t & 63;
  const int tr = t >> 6;
#pragma unroll
  for (int j = 0; j < 16; j++) {
    int r = (j << 2) + tr;
    tile[r][tc] = src[(size_t)(k0 + r) * Csrc + c0 + tc];
  }
  __syncthreads();
#pragma unroll
  for (int j = 0; j < 16; j++) {
    int c  = (j << 2) + tr;
    int gc = c0 + c;
    int np;
    if (mode == 0)      np = gc + rowoff;
    else if (mode == 1) np = ((gc >> 5) << 6) + (gc & 31);
    else if (mode == 2) np = ((gc >> 5) << 6) + 32 + (gc & 31);
    else                np = ((gc >> 4) << 6) + ((mode - 3) << 4) + (gc & 15);
    dst[(size_t)np * Kd + k0 + tc] = f2bf(tile[tc][c]);
    if (mode == 5) dst[(size_t)(np + 16) * Kd + k0 + tc] = 0;   // zero plane 3
  }
}

__global__ void pack_bias(const float* __restrict__ bg, const float* __restrict__ bv,
                          const float* __restrict__ bd, float* __restrict__ bias)
{
  int i = blockIdx.x * 256 + threadIdx.x;
  if (i < DDIM) { bias[i] = bg[i]; bias[i + DDIM] = bv[i]; bias[i + 2 * DDIM] = bd[i]; }
}

// ---------------- RMSNorm: fp32 in -> bf16 out ----------------
__global__ __launch_bounds__(256)
void rmsnorm_kernel(const float* __restrict__ x, const float* __restrict__ w,
                    unsigned short* __restrict__ out)
{
  const int row = blockIdx.x;
  const int t = threadIdx.x;
  const float4 v = reinterpret_cast<const float4*>(x + (size_t)row * DDIM)[t];
  float ss = v.x * v.x + v.y * v.y + v.z * v.z + v.w * v.w;
#pragma unroll
  for (int o = 32; o > 0; o >>= 1) ss += __shfl_down(ss, o);
  __shared__ float wsum[4];
  if ((t & 63) == 0) wsum[t >> 6] = ss;
  __syncthreads();
  float tot = wsum[0] + wsum[1] + wsum[2] + wsum[3];
  const float rms = rsqrtf(tot * (1.0f / DDIM) + 1e-6f);
  const float4 wv = reinterpret_cast<const float4*>(w)[t];
  ushort4 o4;
  o4.x = f2bf(v.x * rms * wv.x);
  o4.y = f2bf(v.y * rms * wv.y);
  o4.z = f2bf(v.z * rms * wv.z);
  o4.w = f2bf(v.w * rms * wv.w);
  reinterpret_cast<ushort4*>(out + (size_t)row * DDIM)[t] = o4;
}

// ---------------- 256x256 8-phase pipelined bf16 MFMA GEMM ----------------
// A [M][K] bf16 row-major, Bt [Np][K] bf16 (pre-transposed weights).
// 512 threads = 8 waves (2M x 4N), per-wave output 128x64.
// LDS 128 KiB: 2 bufs x (A 256x64 + B 256x64), XOR-swizzle byte^=(row&7)<<4
// via pre-swizzled global source. B rows permuted nh-major.
// Pipelined reads: per phase [early ds_read (dead regs)] -> lgkm wait ->
// MFMA -> [late ds_read (regs just consumed, in-order-safe WAR)] -> stage ->
// [vmcnt(6) at ph3/ph7] -> barrier. Waits per half: [4,0,0,none].
// Stage calendar: ph1..4 -> buf0 units {Bnh0,Amh0,Bnh1,Amh1} for tile t2+2;
// ph5..8 -> buf1 units for t2+3. All stage-writes >=1 barrier after the last
// ds_read of the unit's old data; buf completeness via vmcnt one phase early.

#define SB0 __builtin_amdgcn_sched_barrier(0)
#define BAR __builtin_amdgcn_s_barrier()
#define PRIO1 __builtin_amdgcn_s_setprio(1)
#define PRIO0 __builtin_amdgcn_s_setprio(0)
#define WAITL4 do { asm volatile("s_waitcnt lgkmcnt(4)" ::: "memory"); SB0; } while (0)
#define WAITL0 do { asm volatile("s_waitcnt lgkmcnt(0)" ::: "memory"); SB0; } while (0)
#define WAITV6 do { asm volatile("s_waitcnt vmcnt(6)" ::: "memory"); } while (0)
#define WAITV0 do { asm volatile("s_waitcnt vmcnt(0)" ::: "memory"); } while (0)

#define DSR(D, A, O) asm volatile("ds_read_b128 %0, %1 offset:" O : "=v"(D) : "v"(A))
#define RD_AF(O0, O1, O2, O3) do { \
  DSR(af[0][0], aA0, O0); DSR(af[0][1], aA1, O0); \
  DSR(af[1][0], aA0, O1); DSR(af[1][1], aA1, O1); \
  DSR(af[2][0], aA0, O2); DSR(af[2][1], aA1, O2); \
  DSR(af[3][0], aA0, O3); DSR(af[3][1], aA1, O3); } while (0)
#define RD_BF(B, O0, O1) do { \
  DSR(B[0][0], bB0, O0); DSR(B[0][1], bB1, O0); \
  DSR(B[1][0], bB0, O1); DSR(B[1][1], bB1, O1); } while (0)

template<int MH, int NH, bool SKIP1>
__device__ __forceinline__ void mfma_quad(f32x4 (&acc)[8][4], const bf16x8 (&af)[4][2],
                                          const bf16x8 (&bf)[2][2])
{
#pragma unroll
  for (int mf = 0; mf < 4; mf++)
#pragma unroll
    for (int nf = 0; nf < (SKIP1 ? 1 : 2); nf++)
#pragma unroll
      for (int kk = 0; kk < 2; kk++)
        acc[MH * 4 + mf][NH * 2 + nf] = __builtin_amdgcn_mfma_f32_16x16x32_bf16(
            af[mf][kk], bf[nf][kk], acc[MH * 4 + mf][NH * 2 + nf], 0, 0, 0);
}

template<int EPI>
__global__ __launch_bounds__(512, 2)
void gemm256(const unsigned short* __restrict__ A,
             const unsigned short* __restrict__ Bt,
             int Np, int K,
             const float* __restrict__ bias,
             const float* __restrict__ resid,
             float* __restrict__ outf,
             unsigned short* __restrict__ outh)
{
  __shared__ __align__(16) unsigned short ldsA[2][256 * 64];
  __shared__ __align__(16) unsigned short ldsB[2][256 * 64];
  const int tid = threadIdx.x, wid = tid >> 6, lane = tid & 63;
  constexpr bool SK = (EPI == 0);   // mixer: skip pad plane (NH=1, nf=1)

  // bijective XCD swizzle (nwg % 8 == 0 for all our grids)
  const int gx = gridDim.x;
  const int lin = blockIdx.y * gx + blockIdx.x;
  const int cpx = (gx * gridDim.y) >> 3;
  const int swz = (lin & 7) * cpx + (lin >> 3);
  const int bx = swz % gx, by = swz / gx;
  const int m0 = by << 8, n0 = bx << 8;
  const int wr = wid >> 2, wc = wid & 3;

  f32x4 acc[8][4];
  const f32x4 zero = {0.f, 0.f, 0.f, 0.f};
#pragma unroll
  for (int a = 0; a < 8; a++)
#pragma unroll
    for (int j = 0; j < 4; j++) acc[a][j] = zero;

  // ---- staging (global_load_lds, width 16, pre-swizzled source) ----
  const int swzk = (((tid & 7) ^ ((tid >> 3) & 7)) << 3);   // src k-elem pre-swizzle
  auto stA = [&](int p, int u, int t) {
#pragma unroll
    for (int r = 0; r < 2; r++) {
      const int lrow0 = (r << 7) + (u << 6);
      const int grow = m0 + lrow0 + (tid >> 3);
      const unsigned short* src = A + (size_t)grow * K + (t << 6) + swzk;
      unsigned short* dst = &ldsA[p][lrow0 << 6] + (wid << 9);
      __builtin_amdgcn_global_load_lds(
          (const __attribute__((address_space(1))) void*)src,
          (__attribute__((address_space(3))) void*)dst, 16, 0, 0);
    }
  };
  auto stB = [&](int p, int u, int t) {
#pragma unroll
    for (int r = 0; r < 2; r++) {
      const int j = (r << 6) + (tid >> 3);
      const int lrow0 = (u << 7) + (r << 6);
      const int gcol = n0 + ((j >> 5) << 6) + (u << 5) + (j & 31);
      const unsigned short* src = Bt + (size_t)gcol * K + (t << 6) + swzk;
      unsigned short* dst = &ldsB[p][lrow0 << 6] + (wid << 9);
      __builtin_amdgcn_global_load_lds(
          (const __attribute__((address_space(1))) void*)src,
          (__attribute__((address_space(3))) void*)dst, 16, 0, 0);
    }
  };

  // ---- persistent ds_read base addresses (all variation via offset imm) ----
  // byte addr = base + buf*32768 + mh*8192(A)/nh*16384(B) + mf|nf*2048
  const unsigned laneR = (unsigned)((lane & 15) << 7);          // row * 128B
  const unsigned sw    = (unsigned)((lane & 7) << 4);
  const unsigned k0b   = (unsigned)((lane >> 4) << 4);
  const unsigned baseA = (unsigned)(uintptr_t)&ldsA[0][0] + ((unsigned)wr << 14);
  const unsigned baseB = (unsigned)(uintptr_t)&ldsB[0][0] + ((unsigned)wc << 12);
  const unsigned aA0 = baseA + laneR + (k0b ^ sw);
  const unsigned aA1 = baseA + laneR + ((64u + k0b) ^ sw);
  const unsigned bB0 = baseB + laneR + (k0b ^ sw);
  const unsigned bB1 = baseB + laneR + ((64u + k0b) ^ sw);

  bf16x8 af[4][2];      // current mh half of A
  bf16x8 bf0[2][2];     // nh0 B frags
  bf16x8 bf1[2][2];     // nh1 B frags

  const int NITER = (K >> 6) >> 1;   // 2 K-tiles per iteration

  // ---- prologue: tile0 -> buf0, tile1 -> buf1; pre-read mh0/nh0 of tile0 ----
  stB(0, 0, 0); stA(0, 0, 0); stB(0, 1, 0); stA(0, 1, 0);
  stB(1, 0, 1); stA(1, 0, 1); stB(1, 1, 1); stA(1, 1, 1);
  asm volatile("s_waitcnt vmcnt(8)" ::: "memory");   // buf0 complete
  BAR; SB0;
  RD_BF(bf0, "0", "2048");            // nh0(t0), buf0
  RD_AF("0", "2048", "4096", "6144"); // mh0(t0), buf0

  for (int i = 0; i < NITER; i++) {
    const int t2 = i << 1;
    const bool more = (i + 1 < NITER);
    // ---- ph1: Q(0,0) tile t2 ----
    RD_BF(bf1, "16384", "18432");               // early: nh1(t2) buf0
    WAITL4;
    PRIO1; mfma_quad<0, 0, false>(acc, af, bf0); PRIO0; SB0;
    if (more) stB(0, 0, t2 + 2);
    BAR;
    // ---- ph2: Q(0,1) ----
    WAITL0;
    PRIO1; mfma_quad<0, 1, SK>(acc, af, bf1); PRIO0; SB0;
    RD_AF("8192", "10240", "12288", "14336");   // late: mh1(t2) buf0
    if (more) stA(0, 0, t2 + 2);
    BAR;
    // ---- ph3: Q(1,0) ----
    WAITL0;
    PRIO1; mfma_quad<1, 0, false>(acc, af, bf0); PRIO0; SB0;
    if (more) stB(0, 1, t2 + 2);
    if (more) WAITV6; else WAITV0;              // buf1(t2+1) complete
    BAR;
    // ---- ph4: Q(1,1) ----
    RD_BF(bf0, "32768", "34816");               // early: nh0(t2+1) buf1
    PRIO1; mfma_quad<1, 1, SK>(acc, af, bf1); PRIO0; SB0;
    RD_AF("32768", "34816", "36864", "38912");  // late: mh0(t2+1) buf1
    if (more) stA(0, 1, t2 + 2);
    BAR;
    // ---- ph5: Q(0,0) tile t2+1 ----
    RD_BF(bf1, "49152", "51200");               // early: nh1(t2+1) buf1
    WAITL4;
    PRIO1; mfma_quad<0, 0, false>(acc, af, bf0); PRIO0; SB0;
    if (more) stB(1, 0, t2 + 3);
    BAR;
    // ---- ph6: Q(0,1) ----
    WAITL0;
    PRIO1; mfma_quad<0, 1, SK>(acc, af, bf1); PRIO0; SB0;
    RD_AF("40960", "43008", "45056", "47104");  // late: mh1(t2+1) buf1
    if (more) stA(1, 0, t2 + 3);
    BAR;
    // ---- ph7: Q(1,0) ----
    WAITL0;
    PRIO1; mfma_quad<1, 0, false>(acc, af, bf0); PRIO0; SB0;
    if (more) stB(1, 1, t2 + 3);
    if (more) WAITV6;                           // buf0(t2+2) complete
    BAR;
    // ---- ph8: Q(1,1) ----
    RD_BF(bf0, "0", "2048");                    // early: nh0(t2+2) buf0 (stale-read if last)
    PRIO1; mfma_quad<1, 1, SK>(acc, af, bf1); PRIO0; SB0;
    RD_AF("0", "2048", "4096", "6144");         // late: mh0(t2+2) buf0 (stale if last)
    if (more) stA(1, 1, t2 + 3);
    BAR;
  }
  // drain in-flight asm ds_reads before regs get reused by the epilogue
  asm volatile("s_waitcnt lgkmcnt(0)" ::: "memory"); SB0;

  // ---- epilogue: C/D layout col=lane&15, row=(lane>>4)*4+reg [m89] ----
  const int lcol = lane & 15;
  const int rgrp = (lane >> 4) << 2;
  if (EPI == 0) {
    // mixer: j=0 g, j=1 v, j=2 d (plane-interleaved B), j=3 pad (skipped)
    const int ch = (n0 >> 2) + (wc << 4) + lcol;        // channel 0..1023
    const float bgv = bias[ch], bvv = bias[ch + DDIM], bdv = bias[ch + 2 * DDIM];
#pragma unroll
    for (int a = 0; a < 8; a++)
#pragma unroll
      for (int rg = 0; rg < 4; rg++) {
        const int row = m0 + (wr << 7) + (a << 4) + rgrp + rg;
        const float g  = acc[a][0][rg] + bgv;
        const float v  = acc[a][1][rg] + bvv;
        const float dd = acc[a][2][rg] + bdv;
        const float aa = 0.001f + 0.998f * sigmoid_(dd);
        const float xs = sigmoid_(g) * tanh_(v);
        float* o = outf + (size_t)row * (2 * DDIM);
        o[ch] = aa;
        o[ch + DDIM] = xs;
      }
  } else if (EPI == 1) {
    const int tN = Np >> 1;
#pragma unroll
    for (int a = 0; a < 8; a++)
#pragma unroll
      for (int j = 0; j < 2; j++) {
        const int tcol = (n0 >> 1) + (wc << 5) + (j << 4) + lcol;
#pragma unroll
        for (int rg = 0; rg < 4; rg++) {
          const int row = m0 + (wr << 7) + (a << 4) + rgrp + rg;
          const float g = acc[a][j][rg];
          const float u = acc[a][j + 2][rg];
          const float s = g / (1.0f + __expf(-g));      // silu
          outh[(size_t)row * tN + tcol] = f2bf(s * u);
        }
      }
  } else {
#pragma unroll
    for (int a = 0; a < 8; a++)
#pragma unroll
      for (int j = 0; j < 4; j++) {
        const int col = n0 + (wc << 6) + (j << 4) + lcol;
#pragma unroll
        for (int rg = 0; rg < 4; rg++) {
          const int row = m0 + (wr << 7) + (a << 4) + rgrp + rg;
          outf[(size_t)row * Np + col] = acc[a][j][rg] + resid[(size_t)row * Np + col];
        }
      }
  }
}

// ---------------- chunked linear scan over precomputed (a, xs) ----------------
__global__ __launch_bounds__(256)
void scan_phase1(const float* __restrict__ ax, float* __restrict__ Ac, float* __restrict__ Hc)
{
  const int d = blockIdx.x * 256 + threadIdx.x;
  const int ch = blockIdx.y;
  const int b = blockIdx.z;
  size_t base = ((size_t)b * SS + (size_t)ch * CHUNK) * (2 * DDIM) + d;
  float Aprod = 1.0f, H = 0.0f;
  for (int s = 0; s < CHUNK; s++) {
    const float a  = ax[base];
    const float xs = ax[base + DDIM];
    H = a * H + xs;
    Aprod *= a;
    base += 2 * DDIM;
  }
  const int idx = (b * NCH + ch) * DDIM + d;
  Ac[idx] = Aprod;
  Hc[idx] = H;
}

__global__ void scan_phase2(const float* __restrict__ Ac, const float* __restrict__ Hc,
                            float* __restrict__ Hpre)
{
  const int idx = blockIdx.x * 256 + threadIdx.x;
  const int b = idx >> 10, d = idx & (DDIM - 1);
  float h = 0.0f;
  for (int c = 0; c < NCH; c++) {
    const int i = (b * NCH + c) * DDIM + d;
    Hpre[i] = h;
    h = Ac[i] * h + Hc[i];
  }
}

__global__ __launch_bounds__(256)
void scan_phase3(const float* __restrict__ ax, const float* __restrict__ x,
                 const float* __restrict__ Hpre, float* __restrict__ xres)
{
  const int d = blockIdx.x * 256 + threadIdx.x;
  const int ch = blockIdx.y;
  const int b = blockIdx.z;
  float H = Hpre[(b * NCH + ch) * DDIM + d];
  const size_t mbase = (size_t)b * SS + (size_t)ch * CHUNK;
  size_t base  = mbase * (2 * DDIM) + d;
  size_t xbase = mbase * DDIM + d;
  for (int s = 0; s < CHUNK; s++) {
    const float a  = ax[base];
    const float xs = ax[base + DDIM];
    H = a * H + xs;
    xres[xbase] = x[xbase] + H;
    base += 2 * DDIM;
    xbase += DDIM;
  }
}

// ---------------- launch ----------------
extern "C" void kernel_launch(void* const* d_in, const int* in_sizes, int n_in,
                              void* d_out, int out_size, void* d_ws, size_t ws_size,
                              hipStream_t stream)
{
  const float* x         = (const float*)d_in[0];
  const float* w_rms_mix = (const float*)d_in[1];
  const float* w_rms_ffn = (const float*)d_in[2];
  const float* Wg  = (const float*)d_in[3];
  const float* bg  = (const float*)d_in[4];
  const float* Wv  = (const float*)d_in[5];
  const float* bv  = (const float*)d_in[6];
  const float* Wd  = (const float*)d_in[7];
  const float* bd  = (const float*)d_in[8];
  const float* Wga = (const float*)d_in[9];
  const float* Wup = (const float*)d_in[10];
  const float* Wo  = (const float*)d_in[11];
  float* out = (float*)d_out;

  // ---- workspace carve (ws-size adaptive) ----
  char* p = (char*)d_ws;
  auto carve = [&](size_t bytes) -> char* {
    char* r = p; p += (bytes + 255) & ~(size_t)255; return r;
  };
  unsigned short* Wgvd4 = (unsigned short*)carve((size_t)4 * DDIM * DDIM * 2);
  unsigned short* WguT  = (unsigned short*)carve((size_t)2 * FDIM * DDIM * 2);
  unsigned short* WoutT = (unsigned short*)carve((size_t)DDIM * FDIM * 2);
  float* bias = (float*)carve(3 * DDIM * 4);
  const size_t fixed_used = (size_t)(p - (char*)d_ws);

  const size_t xn_b  = (size_t)SS * DDIM * 2;
  const size_t ax_b  = (size_t)SS * 2 * DDIM * 4;
  const size_t ach_b = (size_t)NCH * DDIM * 4;
  const size_t per_batch = xn_b + ax_b + 3 * ach_b + 2048;
  long long avail = (long long)ws_size - (long long)fixed_used;
  int nb = (avail > 0) ? (int)(avail / (long long)per_batch) : 1;
  if (nb < 1) nb = 1;
  if (nb > BB) nb = BB;

  unsigned short* xn = (unsigned short*)carve((size_t)nb * xn_b);
  float* ax   = (float*)carve((size_t)nb * ax_b);
  unsigned short* tact = (unsigned short*)ax;       // aliases ax (dead after scan)
  float* Ac   = (float*)carve((size_t)nb * ach_b);
  float* Hc   = (float*)carve((size_t)nb * ach_b);
  float* Hpre = (float*)carve((size_t)nb * ach_b);

  // ---- pack weights once + bias ----
  pack_w<<<dim3(16, 16), 256, 0, stream>>>(Wg,  Wgvd4, DDIM, DDIM, 3, 0);
  pack_w<<<dim3(16, 16), 256, 0, stream>>>(Wv,  Wgvd4, DDIM, DDIM, 4, 0);
  pack_w<<<dim3(16, 16), 256, 0, stream>>>(Wd,  Wgvd4, DDIM, DDIM, 5, 0);
  pack_w<<<dim3(48, 16), 256, 0, stream>>>(Wga, WguT,  FDIM, DDIM, 1, 0);
  pack_w<<<dim3(48, 16), 256, 0, stream>>>(Wup, WguT,  FDIM, DDIM, 2, 0);
  pack_w<<<dim3(16, 48), 256, 0, stream>>>(Wo,  WoutT, DDIM, FDIM, 0, 0);
  pack_bias<<<4, 256, 0, stream>>>(bg, bv, bd, bias);

  // ---- per-batch-group pipeline ----
  for (int b0 = 0; b0 < BB; b0 += nb) {
    const int n  = (BB - b0 < nb) ? (BB - b0) : nb;
    const int Mg = n * SS;
    const float* xg   = x   + (size_t)b0 * SS * DDIM;
    float*       outg = out + (size_t)b0 * SS * DDIM;

    // rmsnorm #1 -> xn (bf16)
    rmsnorm_kernel<<<Mg, 256, 0, stream>>>(xg, w_rms_mix, xn);

    // mixer GEMM (4-plane padded, pad MFMAs skipped): epilogue -> (a, xs) fp32
    gemm256<0><<<dim3(4 * DDIM / 256, Mg / 256), 512, 0, stream>>>(
        xn, Wgvd4, 4 * DDIM, DDIM, bias, nullptr, ax, nullptr);

    // chunked scan -> outg = x + h
    scan_phase1<<<dim3(DDIM / 256, NCH, n), 256, 0, stream>>>(ax, Ac, Hc);
    scan_phase2<<<(n * DDIM) / 256, 256, 0, stream>>>(Ac, Hc, Hpre);
    scan_phase3<<<dim3(DDIM / 256, NCH, n), 256, 0, stream>>>(ax, xg, Hpre, outg);

    // rmsnorm #2 -> yn (bf16, reuse xn)
    rmsnorm_kernel<<<Mg, 256, 0, stream>>>(outg, w_rms_ffn, xn);

    // FFN1: tact = silu(yn@Wgate) * (yn@Wup)  (bf16, fused epilogue)
    gemm256<1><<<dim3(2 * FDIM / 256, Mg / 256), 512, 0, stream>>>(
        xn, WguT, 2 * FDIM, DDIM, nullptr, nullptr, nullptr, tact);

    // FFN2: outg = tact @ Wout + outg(resid)
    gemm256<2><<<dim3(DDIM / 256, Mg / 256), 512, 0, stream>>>(
        tact, WoutT, DDIM, FDIM, nullptr, outg, outg, nullptr);
  }
}

// Round 6
// 1051.063 us; speedup vs baseline: 1.3307x; 1.0032x over previous
//
#include <hip/hip_runtime.h>

#define BB 8
#define SS 4096
#define DDIM 1024
#define FDIM 3072
#define CHUNK 128
#define NCH (SS/CHUNK)      // 32 chunks per sequence

typedef __attribute__((ext_vector_type(8))) __bf16 bf16x8;
typedef __attribute__((ext_vector_type(4))) float f32x4;

__device__ __forceinline__ unsigned short f2bf(float f) {
  unsigned int u = __builtin_bit_cast(unsigned int, f);
  u += 0x7FFFu + ((u >> 16) & 1u);          // round-to-nearest-even
  return (unsigned short)(u >> 16);
}
__device__ __forceinline__ float sigmoid_(float x) { return 1.0f / (1.0f + __expf(-x)); }
__device__ __forceinline__ float tanh_(float x) {
  float xc = fminf(fmaxf(x, -15.0f), 15.0f);
  float e = __expf(2.0f * xc);
  return (e - 1.0f) / (e + 1.0f);
}

// ---------------- weight transpose + bf16 pack ----------------
__global__ __launch_bounds__(256)
void pack_w(const float* __restrict__ src, unsigned short* __restrict__ dst,
            int Csrc, int Kd, int mode, int rowoff)
{
  __shared__ float tile[64][65];
  const int k0 = blockIdx.y << 6;
  const int c0 = blockIdx.x << 6;
  const int t  = threadIdx.x;
  const int tc = t & 63;
  const int tr = t >> 6;
#pragma unroll
  for (int j = 0; j < 16; j++) {
    int r = (j << 2) + tr;
    tile[r][tc] = src[(size_t)(k0 + r) * Csrc + c0 + tc];
  }
  __syncthreads();
#pragma unroll
  for (int j = 0; j < 16; j++) {
    int c  = (j << 2) + tr;
    int gc = c0 + c;
    int np;
    if (mode == 0)      np = gc + rowoff;
    else if (mode == 1) np = ((gc >> 5) << 6) + (gc & 31);
    else if (mode == 2) np = ((gc >> 5) << 6) + 32 + (gc & 31);
    else                np = ((gc >> 4) << 6) + ((mode - 3) << 4) + (gc & 15);
    dst[(size_t)np * Kd + k0 + tc] = f2bf(tile[tc][c]);
    if (mode == 5) dst[(size_t)(np + 16) * Kd + k0 + tc] = 0;   // zero plane 3
  }
}

__global__ void pack_bias(const float* __restrict__ bg, const float* __restrict__ bv,
                          const float* __restrict__ bd, float* __restrict__ bias)
{
  int i = blockIdx.x * 256 + threadIdx.x;
  if (i < DDIM) { bias[i] = bg[i]; bias[i + DDIM] = bv[i]; bias[i + 2 * DDIM] = bd[i]; }
}

// ---------------- RMSNorm: fp32 in -> bf16 out ----------------
__global__ __launch_bounds__(256)
void rmsnorm_kernel(const float* __restrict__ x, const float* __restrict__ w,
                    unsigned short* __restrict__ out)
{
  const int row = blockIdx.x;
  const int t = threadIdx.x;
  const float4 v = reinterpret_cast<const float4*>(x + (size_t)row * DDIM)[t];
  float ss = v.x * v.x + v.y * v.y + v.z * v.z + v.w * v.w;
#pragma unroll
  for (int o = 32; o > 0; o >>= 1) ss += __shfl_down(ss, o);
  __shared__ float wsum[4];
  if ((t & 63) == 0) wsum[t >> 6] = ss;
  __syncthreads();
  float tot = wsum[0] + wsum[1] + wsum[2] + wsum[3];
  const float rms = rsqrtf(tot * (1.0f / DDIM) + 1e-6f);
  const float4 wv = reinterpret_cast<const float4*>(w)[t];
  ushort4 o4;
  o4.x = f2bf(v.x * rms * wv.x);
  o4.y = f2bf(v.y * rms * wv.y);
  o4.z = f2bf(v.z * rms * wv.z);
  o4.w = f2bf(v.w * rms * wv.w);
  reinterpret_cast<ushort4*>(out + (size_t)row * DDIM)[t] = o4;
}

// ---------------- 256x256 8-phase pipelined bf16 MFMA GEMM ----------------
// A [M][K] bf16 row-major, Bt [Np][K] bf16 (pre-transposed weights).
// 512 threads = 8 waves (2M x 4N), per-wave 128x64. LDS 128 KiB 2-buf.
// XOR-swizzle byte^=(row&7)<<4 via pre-swizzled global source. B rows nh-major.
// R4 skeleton (proven): per phase [early ds_read] -> lgkm wait -> MFMA ->
// [late ds_read] -> stage -> [vmcnt(6) at ph3/ph7] -> barrier.
// R6 delta ONLY: in af-reload phases (ph2/4/6/8) the 16-MFMA cluster is
// split into two 8-MFMA halves; af[0..1] reloads issue between the halves
// (dead regs; second half consumes af[2..3] only). Wait counts unchanged.

#define SB0 __builtin_amdgcn_sched_barrier(0)
#define BAR __builtin_amdgcn_s_barrier()
#define PRIO1 __builtin_amdgcn_s_setprio(1)
#define PRIO0 __builtin_amdgcn_s_setprio(0)
#define WAITL4 do { asm volatile("s_waitcnt lgkmcnt(4)" ::: "memory"); SB0; } while (0)
#define WAITL0 do { asm volatile("s_waitcnt lgkmcnt(0)" ::: "memory"); SB0; } while (0)
#define WAITV6 do { asm volatile("s_waitcnt vmcnt(6)" ::: "memory"); } while (0)
#define WAITV0 do { asm volatile("s_waitcnt vmcnt(0)" ::: "memory"); } while (0)

#define DSR(D, A, O) asm volatile("ds_read_b128 %0, %1 offset:" O : "=v"(D) : "v"(A))
#define RD_BF(B, O0, O1) do { \
  DSR(B[0][0], bB0, O0); DSR(B[0][1], bB1, O0); \
  DSR(B[1][0], bB0, O1); DSR(B[1][1], bB1, O1); } while (0)

template<int MH, int NH, bool SKIP1>
__device__ __forceinline__ void mfma_quad(f32x4 (&acc)[8][4], const bf16x8 (&af)[4][2],
                                          const bf16x8 (&bf)[2][2])
{
#pragma unroll
  for (int mf = 0; mf < 4; mf++)
#pragma unroll
    for (int nf = 0; nf < (SKIP1 ? 1 : 2); nf++)
#pragma unroll
      for (int kk = 0; kk < 2; kk++)
        acc[MH * 4 + mf][NH * 2 + nf] = __builtin_amdgcn_mfma_f32_16x16x32_bf16(
            af[mf][kk], bf[nf][kk], acc[MH * 4 + mf][NH * 2 + nf], 0, 0, 0);
}

// half-quad: H=0 -> mf {0,1}; H=1 -> mf {2,3}
template<int MH, int NH, int H, bool SKIP1>
__device__ __forceinline__ void mfma_quad_h(f32x4 (&acc)[8][4], const bf16x8 (&af)[4][2],
                                            const bf16x8 (&bf)[2][2])
{
#pragma unroll
  for (int mf = H * 2; mf < H * 2 + 2; mf++)
#pragma unroll
    for (int nf = 0; nf < (SKIP1 ? 1 : 2); nf++)
#pragma unroll
      for (int kk = 0; kk < 2; kk++)
        acc[MH * 4 + mf][NH * 2 + nf] = __builtin_amdgcn_mfma_f32_16x16x32_bf16(
            af[mf][kk], bf[nf][kk], acc[MH * 4 + mf][NH * 2 + nf], 0, 0, 0);
}

template<int EPI>
__global__ __launch_bounds__(512, 2)
void gemm256(const unsigned short* __restrict__ A,
             const unsigned short* __restrict__ Bt,
             int Np, int K,
             const float* __restrict__ bias,
             const float* __restrict__ resid,
             float* __restrict__ outf,
             unsigned short* __restrict__ outh)
{
  __shared__ __align__(16) unsigned short ldsA[2][256 * 64];
  __shared__ __align__(16) unsigned short ldsB[2][256 * 64];
  const int tid = threadIdx.x, wid = tid >> 6, lane = tid & 63;
  constexpr bool SK = (EPI == 0);   // mixer: skip pad plane (NH1, nf1)

  // bijective XCD swizzle (nwg % 8 == 0 for all our grids)
  const int gx = gridDim.x;
  const int lin = blockIdx.y * gx + blockIdx.x;
  const int cpx = (gx * gridDim.y) >> 3;
  const int swz = (lin & 7) * cpx + (lin >> 3);
  const int bx = swz % gx, by = swz / gx;
  const int m0 = by << 8, n0 = bx << 8;
  const int wr = wid >> 2, wc = wid & 3;

  f32x4 acc[8][4];
  const f32x4 zero = {0.f, 0.f, 0.f, 0.f};
#pragma unroll
  for (int a = 0; a < 8; a++)
#pragma unroll
    for (int j = 0; j < 4; j++) acc[a][j] = zero;

  // ---- staging (global_load_lds width 16, pre-swizzled source) ----
  const int swzk = (((tid & 7) ^ ((tid >> 3) & 7)) << 3);
  auto stA = [&](int p, int u, int t) {
#pragma unroll
    for (int r = 0; r < 2; r++) {
      const int lrow0 = (r << 7) + (u << 6);
      const int grow = m0 + lrow0 + (tid >> 3);
      const unsigned short* src = A + (size_t)grow * K + (t << 6) + swzk;
      unsigned short* dst = &ldsA[p][lrow0 << 6] + (wid << 9);
      __builtin_amdgcn_global_load_lds(
          (const __attribute__((address_space(1))) void*)src,
          (__attribute__((address_space(3))) void*)dst, 16, 0, 0);
    }
  };
  auto stB = [&](int p, int u, int t) {
#pragma unroll
    for (int r = 0; r < 2; r++) {
      const int j = (r << 6) + (tid >> 3);
      const int lrow0 = (u << 7) + (r << 6);
      const int gcol = n0 + ((j >> 5) << 6) + (u << 5) + (j & 31);
      const unsigned short* src = Bt + (size_t)gcol * K + (t << 6) + swzk;
      unsigned short* dst = &ldsB[p][lrow0 << 6] + (wid << 9);
      __builtin_amdgcn_global_load_lds(
          (const __attribute__((address_space(1))) void*)src,
          (__attribute__((address_space(3))) void*)dst, 16, 0, 0);
    }
  };

  // ---- persistent ds_read bases; variation via offset immediates ----
  // A byte off = buf*32768 + mh*8192 + mf*2048 ; B = buf*32768 + nh*16384 + nf*2048
  const unsigned laneR = (unsigned)((lane & 15) << 7);
  const unsigned sw    = (unsigned)((lane & 7) << 4);
  const unsigned k0b   = (unsigned)((lane >> 4) << 4);
  const unsigned baseA = (unsigned)(uintptr_t)&ldsA[0][0] + ((unsigned)wr << 14);
  const unsigned baseB = (unsigned)(uintptr_t)&ldsB[0][0] + ((unsigned)wc << 12);
  const unsigned aA0 = baseA + laneR + (k0b ^ sw);
  const unsigned aA1 = baseA + laneR + ((64u + k0b) ^ sw);
  const unsigned bB0 = baseB + laneR + (k0b ^ sw);
  const unsigned bB1 = baseB + laneR + ((64u + k0b) ^ sw);

  bf16x8 af[4][2];      // current A half-tile (mh)
  bf16x8 bf0[2][2];     // B nh0 frags
  bf16x8 bf1[2][2];     // B nh1 frags

  const int NITER = (K >> 6) >> 1;

  // ---- prologue: tile0 -> buf0, tile1 -> buf1; prime af(mh0), bf0(nh0) ----
  stB(0, 0, 0); stA(0, 0, 0); stB(0, 1, 0); stA(0, 1, 0);
  stB(1, 0, 1); stA(1, 0, 1); stB(1, 1, 1); stA(1, 1, 1);
  asm volatile("s_waitcnt vmcnt(8)" ::: "memory");   // buf0 complete
  BAR; SB0;
  DSR(af[0][0], aA0, "0");    DSR(af[0][1], aA1, "0");
  DSR(af[1][0], aA0, "2048"); DSR(af[1][1], aA1, "2048");
  DSR(af[2][0], aA0, "4096"); DSR(af[2][1], aA1, "4096");
  DSR(af[3][0], aA0, "6144"); DSR(af[3][1], aA1, "6144");
  DSR(bf0[0][0], bB0, "0");    DSR(bf0[0][1], bB1, "0");
  DSR(bf0[1][0], bB0, "2048"); DSR(bf0[1][1], bB1, "2048");

  for (int i = 0; i < NITER; i++) {
    const int t2 = i << 1;
    const bool more = (i + 1 < NITER);

    // ---- ph1: Q00 (af*bf0, tile t2) | bf1<-nh1(t2) buf0 early ----
    RD_BF(bf1, "16384", "18432");
    WAITL4;
    PRIO1; mfma_quad<0, 0, false>(acc, af, bf0); PRIO0; SB0;
    if (more) stB(0, 0, t2 + 2);
    BAR;

    // ---- ph2: Q01 (af*bf1) | af<-mh1(t2) buf0, half-woven ----
    WAITL0;
    PRIO1; mfma_quad_h<0, 1, 0, SK>(acc, af, bf1); SB0;
    DSR(af[0][0], aA0, "8192");  DSR(af[0][1], aA1, "8192");
    DSR(af[1][0], aA0, "10240"); DSR(af[1][1], aA1, "10240"); SB0;
    mfma_quad_h<0, 1, 1, SK>(acc, af, bf1); PRIO0; SB0;
    DSR(af[2][0], aA0, "12288"); DSR(af[2][1], aA1, "12288");
    DSR(af[3][0], aA0, "14336"); DSR(af[3][1], aA1, "14336");
    if (more) stA(0, 0, t2 + 2);
    BAR;

    // ---- ph3: Q10 (af*bf0) ----
    WAITL0;
    PRIO1; mfma_quad<1, 0, false>(acc, af, bf0); PRIO0; SB0;
    if (more) stB(0, 1, t2 + 2);
    if (more) WAITV6; else WAITV0;              // buf1(t2+1) complete
    BAR;

    // ---- ph4: Q11 | bf0<-nh0(t2+1) buf1 early; af<-mh0(t2+1) buf1 half-woven ----
    RD_BF(bf0, "32768", "34816");
    PRIO1; mfma_quad_h<1, 1, 0, SK>(acc, af, bf1); SB0;
    DSR(af[0][0], aA0, "32768"); DSR(af[0][1], aA1, "32768");
    DSR(af[1][0], aA0, "34816"); DSR(af[1][1], aA1, "34816"); SB0;
    mfma_quad_h<1, 1, 1, SK>(acc, af, bf1); PRIO0; SB0;
    DSR(af[2][0], aA0, "36864"); DSR(af[2][1], aA1, "36864");
    DSR(af[3][0], aA0, "38912"); DSR(af[3][1], aA1, "38912");
    if (more) stA(0, 1, t2 + 2);
    BAR;

    // ---- ph5: Q00 (tile t2+1) | bf1<-nh1(t2+1) buf1 early ----
    RD_BF(bf1, "49152", "51200");
    WAITL4;
    PRIO1; mfma_quad<0, 0, false>(acc, af, bf0); PRIO0; SB0;
    if (more) stB(1, 0, t2 + 3);
    BAR;

    // ---- ph6: Q01 | af<-mh1(t2+1) buf1, half-woven ----
    WAITL0;
    PRIO1; mfma_quad_h<0, 1, 0, SK>(acc, af, bf1); SB0;
    DSR(af[0][0], aA0, "40960"); DSR(af[0][1], aA1, "40960");
    DSR(af[1][0], aA0, "43008"); DSR(af[1][1], aA1, "43008"); SB0;
    mfma_quad_h<0, 1, 1, SK>(acc, af, bf1); PRIO0; SB0;
    DSR(af[2][0], aA0, "45056"); DSR(af[2][1], aA1, "45056");
    DSR(af[3][0], aA0, "47104"); DSR(af[3][1], aA1, "47104");
    if (more) stA(1, 0, t2 + 3);
    BAR;

    // ---- ph7: Q10 ----
    WAITL0;
    PRIO1; mfma_quad<1, 0, false>(acc, af, bf0); PRIO0; SB0;
    if (more) stB(1, 1, t2 + 3);
    if (more) WAITV6;                           // buf0(t2+2) complete
    BAR;

    // ---- ph8: Q11 | bf0<-nh0(t2+2) buf0 early; af<-mh0(t2+2) buf0 half-woven ----
    RD_BF(bf0, "0", "2048");                    // stale-read if last iter (harmless)
    PRIO1; mfma_quad_h<1, 1, 0, SK>(acc, af, bf1); SB0;
    DSR(af[0][0], aA0, "0");    DSR(af[0][1], aA1, "0");
    DSR(af[1][0], aA0, "2048"); DSR(af[1][1], aA1, "2048"); SB0;
    mfma_quad_h<1, 1, 1, SK>(acc, af, bf1); PRIO0; SB0;
    DSR(af[2][0], aA0, "4096"); DSR(af[2][1], aA1, "4096");
    DSR(af[3][0], aA0, "6144"); DSR(af[3][1], aA1, "6144");
    if (more) stA(1, 1, t2 + 3);
    BAR;
  }
  // drain in-flight asm ds_reads before regs are reused by the epilogue
  asm volatile("s_waitcnt lgkmcnt(0)" ::: "memory"); SB0;

  // ---- epilogue: C/D layout col=lane&15, row=(lane>>4)*4+reg [m89] ----
  const int lcol = lane & 15;
  const int rgrp = (lane >> 4) << 2;
  if (EPI == 0) {
    const int ch = (n0 >> 2) + (wc << 4) + lcol;        // channel 0..1023
    const float bgv = bias[ch], bvv = bias[ch + DDIM], bdv = bias[ch + 2 * DDIM];
#pragma unroll
    for (int a = 0; a < 8; a++)
#pragma unroll
      for (int rg = 0; rg < 4; rg++) {
        const int row = m0 + (wr << 7) + (a << 4) + rgrp + rg;
        const float g  = acc[a][0][rg] + bgv;
        const float v  = acc[a][1][rg] + bvv;
        const float dd = acc[a][2][rg] + bdv;
        const float aa = 0.001f + 0.998f * sigmoid_(dd);
        const float xs = sigmoid_(g) * tanh_(v);
        float* o = outf + (size_t)row * (2 * DDIM);
        o[ch] = aa;
        o[ch + DDIM] = xs;
      }
  } else if (EPI == 1) {
    const int tN = Np >> 1;
#pragma unroll
    for (int a = 0; a < 8; a++)
#pragma unroll
      for (int j = 0; j < 2; j++) {
        const int tcol = (n0 >> 1) + (wc << 5) + (j << 4) + lcol;
#pragma unroll
        for (int rg = 0; rg < 4; rg++) {
          const int row = m0 + (wr << 7) + (a << 4) + rgrp + rg;
          const float g = acc[a][j][rg];
          const float u = acc[a][j + 2][rg];
          const float s = g / (1.0f + __expf(-g));      // silu
          outh[(size_t)row * tN + tcol] = f2bf(s * u);
        }
      }
  } else {
#pragma unroll
    for (int a = 0; a < 8; a++)
#pragma unroll
      for (int j = 0; j < 4; j++) {
        const int col = n0 + (wc << 6) + (j << 4) + lcol;
#pragma unroll
        for (int rg = 0; rg < 4; rg++) {
          const int row = m0 + (wr << 7) + (a << 4) + rgrp + rg;
          outf[(size_t)row * Np + col] = acc[a][j][rg] + resid[(size_t)row * Np + col];
        }
      }
  }
}

// ---------------- chunked linear scan over precomputed (a, xs) ----------------
__global__ __launch_bounds__(256)
void scan_phase1(const float* __restrict__ ax, float* __restrict__ Ac, float* __restrict__ Hc)
{
  const int d = blockIdx.x * 256 + threadIdx.x;
  const int ch = blockIdx.y;
  const int b = blockIdx.z;
  size_t base = ((size_t)b * SS + (size_t)ch * CHUNK) * (2 * DDIM) + d;
  float Aprod = 1.0f, H = 0.0f;
  for (int s = 0; s < CHUNK; s++) {
    const float a  = ax[base];
    const float xs = ax[base + DDIM];
    H = a * H + xs;
    Aprod *= a;
    base += 2 * DDIM;
  }
  const int idx = (b * NCH + ch) * DDIM + d;
  Ac[idx] = Aprod;
  Hc[idx] = H;
}

__global__ void scan_phase2(const float* __restrict__ Ac, const float* __restrict__ Hc,
                            float* __restrict__ Hpre)
{
  const int idx = blockIdx.x * 256 + threadIdx.x;
  const int b = idx >> 10, d = idx & (DDIM - 1);
  float h = 0.0f;
  for (int c = 0; c < NCH; c++) {
    const int i = (b * NCH + c) * DDIM + d;
    Hpre[i] = h;
    h = Ac[i] * h + Hc[i];
  }
}

__global__ __launch_bounds__(256)
void scan_phase3(const float* __restrict__ ax, const float* __restrict__ x,
                 const float* __restrict__ Hpre, float* __restrict__ xres)
{
  const int d = blockIdx.x * 256 + threadIdx.x;
  const int ch = blockIdx.y;
  const int b = blockIdx.z;
  float H = Hpre[(b * NCH + ch) * DDIM + d];
  const size_t mbase = (size_t)b * SS + (size_t)ch * CHUNK;
  size_t base  = mbase * (2 * DDIM) + d;
  size_t xbase = mbase * DDIM + d;
  for (int s = 0; s < CHUNK; s++) {
    const float a  = ax[base];
    const float xs = ax[base + DDIM];
    H = a * H + xs;
    xres[xbase] = x[xbase] + H;
    base += 2 * DDIM;
    xbase += DDIM;
  }
}

// ---------------- launch ----------------
extern "C" void kernel_launch(void* const* d_in, const int* in_sizes, int n_in,
                              void* d_out, int out_size, void* d_ws, size_t ws_size,
                              hipStream_t stream)
{
  const float* x         = (const float*)d_in[0];
  const float* w_rms_mix = (const float*)d_in[1];
  const float* w_rms_ffn = (const float*)d_in[2];
  const float* Wg  = (const float*)d_in[3];
  const float* bg  = (const float*)d_in[4];
  const float* Wv  = (const float*)d_in[5];
  const float* bv  = (const float*)d_in[6];
  const float* Wd  = (const float*)d_in[7];
  const float* bd  = (const float*)d_in[8];
  const float* Wga = (const float*)d_in[9];
  const float* Wup = (const float*)d_in[10];
  const float* Wo  = (const float*)d_in[11];
  float* out = (float*)d_out;

  // ---- workspace carve (ws-size adaptive) ----
  char* p = (char*)d_ws;
  auto carve = [&](size_t bytes) -> char* {
    char* r = p; p += (bytes + 255) & ~(size_t)255; return r;
  };
  unsigned short* Wgvd4 = (unsigned short*)carve((size_t)4 * DDIM * DDIM * 2);
  unsigned short* WguT  = (unsigned short*)carve((size_t)2 * FDIM * DDIM * 2);
  unsigned short* WoutT = (unsigned short*)carve((size_t)DDIM * FDIM * 2);
  float* bias = (float*)carve(3 * DDIM * 4);
  const size_t fixed_used = (size_t)(p - (char*)d_ws);

  const size_t xn_b  = (size_t)SS * DDIM * 2;
  const size_t ax_b  = (size_t)SS * 2 * DDIM * 4;
  const size_t ach_b = (size_t)NCH * DDIM * 4;
  const size_t per_batch = xn_b + ax_b + 3 * ach_b + 2048;
  long long avail = (long long)ws_size - (long long)fixed_used;
  int nb = (avail > 0) ? (int)(avail / (long long)per_batch) : 1;
  if (nb < 1) nb = 1;
  if (nb > BB) nb = BB;

  unsigned short* xn = (unsigned short*)carve((size_t)nb * xn_b);
  float* ax   = (float*)carve((size_t)nb * ax_b);
  unsigned short* tact = (unsigned short*)ax;       // aliases ax (dead after scan)
  float* Ac   = (float*)carve((size_t)nb * ach_b);
  float* Hc   = (float*)carve((size_t)nb * ach_b);
  float* Hpre = (float*)carve((size_t)nb * ach_b);

  // ---- pack weights once + bias ----
  pack_w<<<dim3(16, 16), 256, 0, stream>>>(Wg,  Wgvd4, DDIM, DDIM, 3, 0);
  pack_w<<<dim3(16, 16), 256, 0, stream>>>(Wv,  Wgvd4, DDIM, DDIM, 4, 0);
  pack_w<<<dim3(16, 16), 256, 0, stream>>>(Wd,  Wgvd4, DDIM, DDIM, 5, 0);
  pack_w<<<dim3(48, 16), 256, 0, stream>>>(Wga, WguT,  FDIM, DDIM, 1, 0);
  pack_w<<<dim3(48, 16), 256, 0, stream>>>(Wup, WguT,  FDIM, DDIM, 2, 0);
  pack_w<<<dim3(16, 48), 256, 0, stream>>>(Wo,  WoutT, DDIM, FDIM, 0, 0);
  pack_bias<<<4, 256, 0, stream>>>(bg, bv, bd, bias);

  // ---- per-batch-group pipeline ----
  for (int b0 = 0; b0 < BB; b0 += nb) {
    const int n  = (BB - b0 < nb) ? (BB - b0) : nb;
    const int Mg = n * SS;
    const float* xg   = x   + (size_t)b0 * SS * DDIM;
    float*       outg = out + (size_t)b0 * SS * DDIM;

    // rmsnorm #1 -> xn (bf16)
    rmsnorm_kernel<<<Mg, 256, 0, stream>>>(xg, w_rms_mix, xn);

    // mixer GEMM (4-plane padded, pad MFMAs skipped): epilogue -> (a, xs) fp32
    gemm256<0><<<dim3(4 * DDIM / 256, Mg / 256), 512, 0, stream>>>(
        xn, Wgvd4, 4 * DDIM, DDIM, bias, nullptr, ax, nullptr);

    // chunked scan -> outg = x + h
    scan_phase1<<<dim3(DDIM / 256, NCH, n), 256, 0, stream>>>(ax, Ac, Hc);
    scan_phase2<<<(n * DDIM) / 256, 256, 0, stream>>>(Ac, Hc, Hpre);
    scan_phase3<<<dim3(DDIM / 256, NCH, n), 256, 0, stream>>>(ax, xg, Hpre, outg);

    // rmsnorm #2 -> yn (bf16, reuse xn)
    rmsnorm_kernel<<<Mg, 256, 0, stream>>>(outg, w_rms_ffn, xn);

    // FFN1: tact = silu(yn@Wgate) * (yn@Wup)  (bf16, fused epilogue)
    gemm256<1><<<dim3(2 * FDIM / 256, Mg / 256), 512, 0, stream>>>(
        xn, WguT, 2 * FDIM, DDIM, nullptr, nullptr, nullptr, tact);

    // FFN2: outg = tact @ Wout + outg(resid)
    gemm256<2><<<dim3(DDIM / 256, Mg / 256), 512, 0, stream>>>(
        tact, WoutT, DDIM, FDIM, nullptr, outg, outg, nullptr);
  }
}

// Round 7
// 1026.250 us; speedup vs baseline: 1.3629x; 1.0242x over previous
//
#include <hip/hip_runtime.h>
#include <hip/hip_fp16.h>

#define BB 8
#define SS 4096
#define DDIM 1024
#define FDIM 3072
#define CHUNK 128
#define NCH (SS/CHUNK)      // 32 chunks per sequence

typedef __attribute__((ext_vector_type(8))) __bf16 bf16x8;
typedef __attribute__((ext_vector_type(4))) float f32x4;
typedef __attribute__((ext_vector_type(16))) float f32x16;

__device__ __forceinline__ unsigned short f2bf(float f) {
  unsigned int u = __builtin_bit_cast(unsigned int, f);
  u += 0x7FFFu + ((u >> 16) & 1u);          // round-to-nearest-even
  return (unsigned short)(u >> 16);
}
__device__ __forceinline__ float sigmoid_(float x) { return 1.0f / (1.0f + __expf(-x)); }
__device__ __forceinline__ float tanh_(float x) {
  float xc = fminf(fmaxf(x, -15.0f), 15.0f);
  float e = __expf(2.0f * xc);
  return (e - 1.0f) / (e + 1.0f);
}

// ---------------- weight transpose + bf16 pack ----------------
__global__ __launch_bounds__(256)
void pack_w(const float* __restrict__ src, unsigned short* __restrict__ dst,
            int Csrc, int Kd, int mode, int rowoff)
{
  __shared__ float tile[64][65];
  const int k0 = blockIdx.y << 6;
  const int c0 = blockIdx.x << 6;
  const int t  = threadIdx.x;
  const int tc = t & 63;
  const int tr = t >> 6;
#pragma unroll
  for (int j = 0; j < 16; j++) {
    int r = (j << 2) + tr;
    tile[r][tc] = src[(size_t)(k0 + r) * Csrc + c0 + tc];
  }
  __syncthreads();
#pragma unroll
  for (int j = 0; j < 16; j++) {
    int c  = (j << 2) + tr;
    int gc = c0 + c;
    int np;
    if (mode == 0)      np = gc + rowoff;
    else if (mode == 1) np = ((gc >> 5) << 6) + (gc & 31);
    else if (mode == 2) np = ((gc >> 5) << 6) + 32 + (gc & 31);
    else                np = ((gc >> 4) << 6) + ((mode - 3) << 4) + (gc & 15);
    dst[(size_t)np * Kd + k0 + tc] = f2bf(tile[tc][c]);
    if (mode == 5) dst[(size_t)(np + 16) * Kd + k0 + tc] = 0;   // zero plane 3
  }
}

__global__ void pack_bias(const float* __restrict__ bg, const float* __restrict__ bv,
                          const float* __restrict__ bd, float* __restrict__ bias)
{
  int i = blockIdx.x * 256 + threadIdx.x;
  if (i < DDIM) { bias[i] = bg[i]; bias[i + DDIM] = bv[i]; bias[i + 2 * DDIM] = bd[i]; }
}

// ---------------- RMSNorm: fp32 in -> bf16 out ----------------
__global__ __launch_bounds__(256)
void rmsnorm_kernel(const float* __restrict__ x, const float* __restrict__ w,
                    unsigned short* __restrict__ out)
{
  const int row = blockIdx.x;
  const int t = threadIdx.x;
  const float4 v = reinterpret_cast<const float4*>(x + (size_t)row * DDIM)[t];
  float ss = v.x * v.x + v.y * v.y + v.z * v.z + v.w * v.w;
#pragma unroll
  for (int o = 32; o > 0; o >>= 1) ss += __shfl_down(ss, o);
  __shared__ float wsum[4];
  if ((t & 63) == 0) wsum[t >> 6] = ss;
  __syncthreads();
  float tot = wsum[0] + wsum[1] + wsum[2] + wsum[3];
  const float rms = rsqrtf(tot * (1.0f / DDIM) + 1e-6f);
  const float4 wv = reinterpret_cast<const float4*>(w)[t];
  ushort4 o4;
  o4.x = f2bf(v.x * rms * wv.x);
  o4.y = f2bf(v.y * rms * wv.y);
  o4.z = f2bf(v.z * rms * wv.z);
  o4.w = f2bf(v.w * rms * wv.w);
  reinterpret_cast<ushort4*>(out + (size_t)row * DDIM)[t] = o4;
}

// ---------------- shared schedule macros ----------------
#define SB0 __builtin_amdgcn_sched_barrier(0)
#define BAR __builtin_amdgcn_s_barrier()
#define PRIO1 __builtin_amdgcn_s_setprio(1)
#define PRIO0 __builtin_amdgcn_s_setprio(0)
#define WAITL4 do { asm volatile("s_waitcnt lgkmcnt(4)" ::: "memory"); SB0; } while (0)
#define WAITL0 do { asm volatile("s_waitcnt lgkmcnt(0)" ::: "memory"); SB0; } while (0)
#define WAITV6 do { asm volatile("s_waitcnt vmcnt(6)" ::: "memory"); } while (0)
#define WAITV0 do { asm volatile("s_waitcnt vmcnt(0)" ::: "memory"); } while (0)
#define DSR(D, A, O) asm volatile("ds_read_b128 %0, %1 offset:" O : "=v"(D) : "v"(A))

// ================= 16x16 kernel (mixer EPI0 only) =================
#define RD_BF(B, O0, O1) do { \
  DSR(B[0][0], bB0, O0); DSR(B[0][1], bB1, O0); \
  DSR(B[1][0], bB0, O1); DSR(B[1][1], bB1, O1); } while (0)

template<int MH, int NH, bool SKIP1>
__device__ __forceinline__ void mfma_quad(f32x4 (&acc)[8][4], const bf16x8 (&af)[4][2],
                                          const bf16x8 (&bf)[2][2])
{
#pragma unroll
  for (int mf = 0; mf < 4; mf++)
#pragma unroll
    for (int nf = 0; nf < (SKIP1 ? 1 : 2); nf++)
#pragma unroll
      for (int kk = 0; kk < 2; kk++)
        acc[MH * 4 + mf][NH * 2 + nf] = __builtin_amdgcn_mfma_f32_16x16x32_bf16(
            af[mf][kk], bf[nf][kk], acc[MH * 4 + mf][NH * 2 + nf], 0, 0, 0);
}
template<int MH, int NH, int H, bool SKIP1>
__device__ __forceinline__ void mfma_quad_h(f32x4 (&acc)[8][4], const bf16x8 (&af)[4][2],
                                            const bf16x8 (&bf)[2][2])
{
#pragma unroll
  for (int mf = H * 2; mf < H * 2 + 2; mf++)
#pragma unroll
    for (int nf = 0; nf < (SKIP1 ? 1 : 2); nf++)
#pragma unroll
      for (int kk = 0; kk < 2; kk++)
        acc[MH * 4 + mf][NH * 2 + nf] = __builtin_amdgcn_mfma_f32_16x16x32_bf16(
            af[mf][kk], bf[nf][kk], acc[MH * 4 + mf][NH * 2 + nf], 0, 0, 0);
}

// mixer: A@Wgvd4 (16-col g/v/d/pad planes), epilogue -> (om=1-a, xs) fp16
__global__ __launch_bounds__(512, 2)
void gemm_mix(const unsigned short* __restrict__ A,
              const unsigned short* __restrict__ Bt,
              int Np, int K,
              const float* __restrict__ bias,
              __half* __restrict__ axh)
{
  __shared__ __align__(16) unsigned short ldsA[2][256 * 64];
  __shared__ __align__(16) unsigned short ldsB[2][256 * 64];
  const int tid = threadIdx.x, wid = tid >> 6, lane = tid & 63;
  constexpr bool SK = true;   // skip pad plane

  const int gx = gridDim.x;
  const int lin = blockIdx.y * gx + blockIdx.x;
  const int cpx = (gx * gridDim.y) >> 3;
  const int swz = (lin & 7) * cpx + (lin >> 3);
  const int bx = swz % gx, by = swz / gx;
  const int m0 = by << 8, n0 = bx << 8;
  const int wr = wid >> 2, wc = wid & 3;

  f32x4 acc[8][4];
  const f32x4 zero = {0.f, 0.f, 0.f, 0.f};
#pragma unroll
  for (int a = 0; a < 8; a++)
#pragma unroll
    for (int j = 0; j < 4; j++) acc[a][j] = zero;

  const int swzk = (((tid & 7) ^ ((tid >> 3) & 7)) << 3);
  auto stA = [&](int p, int u, int t) {
#pragma unroll
    for (int r = 0; r < 2; r++) {
      const int lrow0 = (r << 7) + (u << 6);
      const int grow = m0 + lrow0 + (tid >> 3);
      const unsigned short* src = A + (size_t)grow * K + (t << 6) + swzk;
      unsigned short* dst = &ldsA[p][lrow0 << 6] + (wid << 9);
      __builtin_amdgcn_global_load_lds(
          (const __attribute__((address_space(1))) void*)src,
          (__attribute__((address_space(3))) void*)dst, 16, 0, 0);
    }
  };
  auto stB = [&](int p, int u, int t) {
#pragma unroll
    for (int r = 0; r < 2; r++) {
      const int j = (r << 6) + (tid >> 3);
      const int lrow0 = (u << 7) + (r << 6);
      const int gcol = n0 + ((j >> 5) << 6) + (u << 5) + (j & 31);
      const unsigned short* src = Bt + (size_t)gcol * K + (t << 6) + swzk;
      unsigned short* dst = &ldsB[p][lrow0 << 6] + (wid << 9);
      __builtin_amdgcn_global_load_lds(
          (const __attribute__((address_space(1))) void*)src,
          (__attribute__((address_space(3))) void*)dst, 16, 0, 0);
    }
  };

  const unsigned laneR = (unsigned)((lane & 15) << 7);
  const unsigned sw    = (unsigned)((lane & 7) << 4);
  const unsigned k0b   = (unsigned)((lane >> 4) << 4);
  const unsigned baseA = (unsigned)(uintptr_t)&ldsA[0][0] + ((unsigned)wr << 14);
  const unsigned baseB = (unsigned)(uintptr_t)&ldsB[0][0] + ((unsigned)wc << 12);
  const unsigned aA0 = baseA + laneR + (k0b ^ sw);
  const unsigned aA1 = baseA + laneR + ((64u + k0b) ^ sw);
  const unsigned bB0 = baseB + laneR + (k0b ^ sw);
  const unsigned bB1 = baseB + laneR + ((64u + k0b) ^ sw);

  bf16x8 af[4][2];
  bf16x8 bf0[2][2];
  bf16x8 bf1[2][2];

  const int NITER = (K >> 6) >> 1;

  stB(0, 0, 0); stA(0, 0, 0); stB(0, 1, 0); stA(0, 1, 0);
  stB(1, 0, 1); stA(1, 0, 1); stB(1, 1, 1); stA(1, 1, 1);
  asm volatile("s_waitcnt vmcnt(8)" ::: "memory");
  BAR; SB0;
  DSR(af[0][0], aA0, "0");    DSR(af[0][1], aA1, "0");
  DSR(af[1][0], aA0, "2048"); DSR(af[1][1], aA1, "2048");
  DSR(af[2][0], aA0, "4096"); DSR(af[2][1], aA1, "4096");
  DSR(af[3][0], aA0, "6144"); DSR(af[3][1], aA1, "6144");
  DSR(bf0[0][0], bB0, "0");    DSR(bf0[0][1], bB1, "0");
  DSR(bf0[1][0], bB0, "2048"); DSR(bf0[1][1], bB1, "2048");

  for (int i = 0; i < NITER; i++) {
    const int t2 = i << 1;
    const bool more = (i + 1 < NITER);

    RD_BF(bf1, "16384", "18432");
    WAITL4;
    PRIO1; mfma_quad<0, 0, false>(acc, af, bf0); PRIO0; SB0;
    if (more) stB(0, 0, t2 + 2);
    BAR;

    WAITL0;
    PRIO1; mfma_quad_h<0, 1, 0, SK>(acc, af, bf1); SB0;
    DSR(af[0][0], aA0, "8192");  DSR(af[0][1], aA1, "8192");
    DSR(af[1][0], aA0, "10240"); DSR(af[1][1], aA1, "10240"); SB0;
    mfma_quad_h<0, 1, 1, SK>(acc, af, bf1); PRIO0; SB0;
    DSR(af[2][0], aA0, "12288"); DSR(af[2][1], aA1, "12288");
    DSR(af[3][0], aA0, "14336"); DSR(af[3][1], aA1, "14336");
    if (more) stA(0, 0, t2 + 2);
    BAR;

    WAITL0;
    PRIO1; mfma_quad<1, 0, false>(acc, af, bf0); PRIO0; SB0;
    if (more) stB(0, 1, t2 + 2);
    if (more) WAITV6; else WAITV0;
    BAR;

    RD_BF(bf0, "32768", "34816");
    PRIO1; mfma_quad_h<1, 1, 0, SK>(acc, af, bf1); SB0;
    DSR(af[0][0], aA0, "32768"); DSR(af[0][1], aA1, "32768");
    DSR(af[1][0], aA0, "34816"); DSR(af[1][1], aA1, "34816"); SB0;
    mfma_quad_h<1, 1, 1, SK>(acc, af, bf1); PRIO0; SB0;
    DSR(af[2][0], aA0, "36864"); DSR(af[2][1], aA1, "36864");
    DSR(af[3][0], aA0, "38912"); DSR(af[3][1], aA1, "38912");
    if (more) stA(0, 1, t2 + 2);
    BAR;

    RD_BF(bf1, "49152", "51200");
    WAITL4;
    PRIO1; mfma_quad<0, 0, false>(acc, af, bf0); PRIO0; SB0;
    if (more) stB(1, 0, t2 + 3);
    BAR;

    WAITL0;
    PRIO1; mfma_quad_h<0, 1, 0, SK>(acc, af, bf1); SB0;
    DSR(af[0][0], aA0, "40960"); DSR(af[0][1], aA1, "40960");
    DSR(af[1][0], aA0, "43008"); DSR(af[1][1], aA1, "43008"); SB0;
    mfma_quad_h<0, 1, 1, SK>(acc, af, bf1); PRIO0; SB0;
    DSR(af[2][0], aA0, "45056"); DSR(af[2][1], aA1, "45056");
    DSR(af[3][0], aA0, "47104"); DSR(af[3][1], aA1, "47104");
    if (more) stA(1, 0, t2 + 3);
    BAR;

    WAITL0;
    PRIO1; mfma_quad<1, 0, false>(acc, af, bf0); PRIO0; SB0;
    if (more) stB(1, 1, t2 + 3);
    if (more) WAITV6;
    BAR;

    RD_BF(bf0, "0", "2048");
    PRIO1; mfma_quad_h<1, 1, 0, SK>(acc, af, bf1); SB0;
    DSR(af[0][0], aA0, "0");    DSR(af[0][1], aA1, "0");
    DSR(af[1][0], aA0, "2048"); DSR(af[1][1], aA1, "2048"); SB0;
    mfma_quad_h<1, 1, 1, SK>(acc, af, bf1); PRIO0; SB0;
    DSR(af[2][0], aA0, "4096"); DSR(af[2][1], aA1, "4096");
    DSR(af[3][0], aA0, "6144"); DSR(af[3][1], aA1, "6144");
    if (more) stA(1, 1, t2 + 3);
    BAR;
  }
  asm volatile("s_waitcnt lgkmcnt(0)" ::: "memory"); SB0;

  // epilogue: (om = 1-a, xs) fp16
  const int lcol = lane & 15;
  const int rgrp = (lane >> 4) << 2;
  const int ch = (n0 >> 2) + (wc << 4) + lcol;        // channel 0..1023
  const float bgv = bias[ch], bvv = bias[ch + DDIM], bdv = bias[ch + 2 * DDIM];
#pragma unroll
  for (int a = 0; a < 8; a++)
#pragma unroll
    for (int rg = 0; rg < 4; rg++) {
      const int row = m0 + (wr << 7) + (a << 4) + rgrp + rg;
      const float g  = acc[a][0][rg] + bgv;
      const float v  = acc[a][1][rg] + bvv;
      const float dd = acc[a][2][rg] + bdv;
      const float om = 0.998f * sigmoid_(-dd) + 0.001f;   // 1 - a
      const float xs = sigmoid_(g) * tanh_(v);
      __half* o = axh + (size_t)row * (2 * DDIM);
      o[ch] = __float2half_rn(om);
      o[ch + DDIM] = __float2half_rn(xs);
    }
}

// ================= 32x32 kernel (FFN1 / FFN2) =================
// Fragment layout (m74/m101): A row=lane&31, k=(lane>>5)*8+e; C/D col=lane&31,
// row=(reg&3)+8*(reg>>2)+4*(lane>>5). Same LDS layouts & stage calendar as 16x16.
#define M32(P, MI, NF, KS, BF) \
  acc[(P)*2+(MI)][NF] = __builtin_amdgcn_mfma_f32_32x32x16_bf16( \
      af[MI][KS], BF[KS], acc[(P)*2+(MI)][NF], 0, 0, 0)
#define Q32(P, NF, BF) do { \
  M32(P,0,NF,0,BF); M32(P,1,NF,0,BF); M32(P,0,NF,1,BF); M32(P,1,NF,1,BF); \
  M32(P,0,NF,2,BF); M32(P,1,NF,2,BF); M32(P,0,NF,3,BF); M32(P,1,NF,3,BF); } while (0)
#define RDA_PAIR(KS, O0, O1) do { \
  DSR(af[0][KS], aK##KS, O0); DSR(af[1][KS], aK##KS, O1); } while (0)
// woven quadrant: after each ks-pair of MFMAs, reload that ks (dead regs, WAR-safe)
#define QW(P, NF, BF, O0, O1) do { \
  M32(P,0,NF,0,BF); M32(P,1,NF,0,BF); SB0; RDA_PAIR(0, O0, O1); SB0; \
  M32(P,0,NF,1,BF); M32(P,1,NF,1,BF); SB0; RDA_PAIR(1, O0, O1); SB0; \
  M32(P,0,NF,2,BF); M32(P,1,NF,2,BF); SB0; RDA_PAIR(2, O0, O1); SB0; \
  M32(P,0,NF,3,BF); M32(P,1,NF,3,BF); SB0; RDA_PAIR(3, O0, O1); SB0; } while (0)
#define RDB4(B, O) do { DSR(B[0], bK0, O); DSR(B[1], bK1, O); \
                        DSR(B[2], bK2, O); DSR(B[3], bK3, O); } while (0)

template<int EPI>
__global__ __launch_bounds__(512, 2)
void gemm256w(const unsigned short* __restrict__ A,
              const unsigned short* __restrict__ Bt,
              int Np, int K,
              const float* __restrict__ resid,
              float* __restrict__ outf,
              unsigned short* __restrict__ outh)
{
  __shared__ __align__(16) unsigned short ldsA[2][256 * 64];
  __shared__ __align__(16) unsigned short ldsB[2][256 * 64];
  const int tid = threadIdx.x, wid = tid >> 6, lane = tid & 63;

  const int gx = gridDim.x;
  const int lin = blockIdx.y * gx + blockIdx.x;
  const int cpx = (gx * gridDim.y) >> 3;
  const int swz = (lin & 7) * cpx + (lin >> 3);
  const int bx = swz % gx, by = swz / gx;
  const int m0 = by << 8, n0 = bx << 8;
  const int wr = wid >> 2, wc = wid & 3;

  f32x16 acc[4][2];
#pragma unroll
  for (int a = 0; a < 4; a++)
#pragma unroll
    for (int j = 0; j < 2; j++)
#pragma unroll
      for (int r = 0; r < 16; r++) acc[a][j][r] = 0.f;

  const int swzk = (((tid & 7) ^ ((tid >> 3) & 7)) << 3);
  auto stA = [&](int p, int u, int t) {
#pragma unroll
    for (int r = 0; r < 2; r++) {
      const int lrow0 = (r << 7) + (u << 6);
      const int grow = m0 + lrow0 + (tid >> 3);
      const unsigned short* src = A + (size_t)grow * K + (t << 6) + swzk;
      unsigned short* dst = &ldsA[p][lrow0 << 6] + (wid << 9);
      __builtin_amdgcn_global_load_lds(
          (const __attribute__((address_space(1))) void*)src,
          (__attribute__((address_space(3))) void*)dst, 16, 0, 0);
    }
  };
  auto stB = [&](int p, int u, int t) {
#pragma unroll
    for (int r = 0; r < 2; r++) {
      const int j = (r << 6) + (tid >> 3);
      const int lrow0 = (u << 7) + (r << 6);
      const int gcol = n0 + ((j >> 5) << 6) + (u << 5) + (j & 31);
      const unsigned short* src = Bt + (size_t)gcol * K + (t << 6) + swzk;
      unsigned short* dst = &ldsB[p][lrow0 << 6] + (wid << 9);
      __builtin_amdgcn_global_load_lds(
          (const __attribute__((address_space(1))) void*)src,
          (__attribute__((address_space(3))) void*)dst, 16, 0, 0);
    }
  };

  // ds_read bases: one per k-step; A imm = buf*32768 + mf*4096; B imm = buf*32768 + nf*16384
  const unsigned l31r = (unsigned)((lane & 31) << 7);
  const unsigned sw   = (unsigned)((lane & 7) << 4);
  const unsigned kh   = (unsigned)((lane >> 5) << 4);
  const unsigned baseA = (unsigned)(uintptr_t)&ldsA[0][0] + ((unsigned)wr << 14);
  const unsigned baseB = (unsigned)(uintptr_t)&ldsB[0][0] + ((unsigned)wc << 12);
  const unsigned aK0 = baseA + l31r + ((0u   + kh) ^ sw);
  const unsigned aK1 = baseA + l31r + ((32u  + kh) ^ sw);
  const unsigned aK2 = baseA + l31r + ((64u  + kh) ^ sw);
  const unsigned aK3 = baseA + l31r + ((96u  + kh) ^ sw);
  const unsigned bK0 = baseB + l31r + ((0u   + kh) ^ sw);
  const unsigned bK1 = baseB + l31r + ((32u  + kh) ^ sw);
  const unsigned bK2 = baseB + l31r + ((64u  + kh) ^ sw);
  const unsigned bK3 = baseB + l31r + ((96u  + kh) ^ sw);

  bf16x8 af[2][4];     // current A half (2 mf x 4 ks)
  bf16x8 bf0[4];       // B nf0 (4 ks)
  bf16x8 bf1[4];       // B nf1

  const int NITER = (K >> 6) >> 1;

  stB(0, 0, 0); stA(0, 0, 0); stB(0, 1, 0); stA(0, 1, 0);
  stB(1, 0, 1); stA(1, 0, 1); stB(1, 1, 1); stA(1, 1, 1);
  asm volatile("s_waitcnt vmcnt(8)" ::: "memory");
  BAR; SB0;
  DSR(af[0][0], aK0, "0");    DSR(af[0][1], aK1, "0");
  DSR(af[0][2], aK2, "0");    DSR(af[0][3], aK3, "0");
  DSR(af[1][0], aK0, "4096"); DSR(af[1][1], aK1, "4096");
  DSR(af[1][2], aK2, "4096"); DSR(af[1][3], aK3, "4096");
  RDB4(bf0, "0");

  for (int i = 0; i < NITER; i++) {
    const int t2 = i << 1;
    const bool more = (i + 1 < NITER);

    // ph1: Q(0,0) tile t2 | bf1<-nf1(t2) buf0 early
    RDB4(bf1, "16384");
    WAITL4;
    PRIO1; Q32(0, 0, bf0); PRIO0; SB0;
    if (more) stB(0, 0, t2 + 2);
    BAR;
    // ph2: Q(0,1) | af<-half1(t2) buf0 woven
    WAITL0;
    PRIO1; QW(0, 1, bf1, "8192", "12288"); PRIO0; SB0;
    if (more) stA(0, 0, t2 + 2);
    BAR;
    // ph3: Q(1,0)
    WAITL0;
    PRIO1; Q32(1, 0, bf0); PRIO0; SB0;
    if (more) stB(0, 1, t2 + 2);
    if (more) WAITV6; else WAITV0;
    BAR;
    // ph4: Q(1,1) | bf0<-nf0(t2+1) buf1 early; af<-half0(t2+1) buf1 woven
    RDB4(bf0, "32768");
    PRIO1; QW(1, 1, bf1, "32768", "36864"); PRIO0; SB0;
    if (more) stA(0, 1, t2 + 2);
    BAR;
    // ph5: Q(0,0) tile t2+1 | bf1<-nf1(t2+1) buf1 early
    RDB4(bf1, "49152");
    WAITL4;
    PRIO1; Q32(0, 0, bf0); PRIO0; SB0;
    if (more) stB(1, 0, t2 + 3);
    BAR;
    // ph6: Q(0,1) | af<-half1(t2+1) buf1 woven
    WAITL0;
    PRIO1; QW(0, 1, bf1, "40960", "45056"); PRIO0; SB0;
    if (more) stA(1, 0, t2 + 3);
    BAR;
    // ph7: Q(1,0)
    WAITL0;
    PRIO1; Q32(1, 0, bf0); PRIO0; SB0;
    if (more) stB(1, 1, t2 + 3);
    if (more) WAITV6;
    BAR;
    // ph8: Q(1,1) | bf0<-nf0(t2+2) buf0 early; af<-half0(t2+2) buf0 woven
    RDB4(bf0, "0");
    PRIO1; QW(1, 1, bf1, "0", "4096"); PRIO0; SB0;
    if (more) stA(1, 1, t2 + 3);
    BAR;
  }
  asm volatile("s_waitcnt lgkmcnt(0)" ::: "memory"); SB0;

  // epilogue: 32x32 C/D: col=lane&31, row=(reg&3)+8*(reg>>2)+4*(lane>>5) [m74/m101]
  const int l31 = lane & 31;
  const int rl  = (lane >> 5) << 2;
  if (EPI == 1) {
    const int tN = Np >> 1;
    const int tcol = (n0 >> 1) + (wc << 5) + l31;
#pragma unroll
    for (int mf = 0; mf < 4; mf++)
#pragma unroll
      for (int rg = 0; rg < 16; rg++) {
        const int row = m0 + (wr << 7) + (mf << 5) + (rg & 3) + ((rg >> 2) << 3) + rl;
        const float g = acc[mf][0][rg];
        const float u = acc[mf][1][rg];
        const float s = g / (1.0f + __expf(-g));      // silu
        outh[(size_t)row * tN + tcol] = f2bf(s * u);
      }
  } else {
#pragma unroll
    for (int mf = 0; mf < 4; mf++)
#pragma unroll
      for (int nf = 0; nf < 2; nf++) {
        const int col = n0 + (wc << 6) + (nf << 5) + l31;
#pragma unroll
        for (int rg = 0; rg < 16; rg++) {
          const int row = m0 + (wr << 7) + (mf << 5) + (rg & 3) + ((rg >> 2) << 3) + rl;
          outf[(size_t)row * Np + col] = acc[mf][nf][rg] + resid[(size_t)row * Np + col];
        }
      }
  }
}

// ---------------- chunked linear scan over fp16 (om=1-a, xs) ----------------
__global__ __launch_bounds__(256)
void scan_phase1(const __half* __restrict__ ax, float* __restrict__ Ac, float* __restrict__ Hc)
{
  const int d = blockIdx.x * 256 + threadIdx.x;
  const int ch = blockIdx.y;
  const int b = blockIdx.z;
  size_t base = ((size_t)b * SS + (size_t)ch * CHUNK) * (2 * DDIM) + d;
  float Aprod = 1.0f, H = 0.0f;
  for (int s = 0; s < CHUNK; s++) {
    const float a  = 1.0f - __half2float(ax[base]);
    const float xs = __half2float(ax[base + DDIM]);
    H = a * H + xs;
    Aprod *= a;
    base += 2 * DDIM;
  }
  const int idx = (b * NCH + ch) * DDIM + d;
  Ac[idx] = Aprod;
  Hc[idx] = H;
}

__global__ void scan_phase2(const float* __restrict__ Ac, const float* __restrict__ Hc,
                            float* __restrict__ Hpre)
{
  const int idx = blockIdx.x * 256 + threadIdx.x;
  const int b = idx >> 10, d = idx & (DDIM - 1);
  float h = 0.0f;
  for (int c = 0; c < NCH; c++) {
    const int i = (b * NCH + c) * DDIM + d;
    Hpre[i] = h;
    h = Ac[i] * h + Hc[i];
  }
}

__global__ __launch_bounds__(256)
void scan_phase3(const __half* __restrict__ ax, const float* __restrict__ x,
                 const float* __restrict__ Hpre, float* __restrict__ xres)
{
  const int d = blockIdx.x * 256 + threadIdx.x;
  const int ch = blockIdx.y;
  const int b = blockIdx.z;
  float H = Hpre[(b * NCH + ch) * DDIM + d];
  const size_t mbase = (size_t)b * SS + (size_t)ch * CHUNK;
  size_t base  = mbase * (2 * DDIM) + d;
  size_t xbase = mbase * DDIM + d;
  for (int s = 0; s < CHUNK; s++) {
    const float a  = 1.0f - __half2float(ax[base]);
    const float xs = __half2float(ax[base + DDIM]);
    H = a * H + xs;
    xres[xbase] = x[xbase] + H;
    base += 2 * DDIM;
    xbase += DDIM;
  }
}

// ---------------- launch ----------------
extern "C" void kernel_launch(void* const* d_in, const int* in_sizes, int n_in,
                              void* d_out, int out_size, void* d_ws, size_t ws_size,
                              hipStream_t stream)
{
  const float* x         = (const float*)d_in[0];
  const float* w_rms_mix = (const float*)d_in[1];
  const float* w_rms_ffn = (const float*)d_in[2];
  const float* Wg  = (const float*)d_in[3];
  const float* bg  = (const float*)d_in[4];
  const float* Wv  = (const float*)d_in[5];
  const float* bv  = (const float*)d_in[6];
  const float* Wd  = (const float*)d_in[7];
  const float* bd  = (const float*)d_in[8];
  const float* Wga = (const float*)d_in[9];
  const float* Wup = (const float*)d_in[10];
  const float* Wo  = (const float*)d_in[11];
  float* out = (float*)d_out;

  // ---- workspace carve (ws-size adaptive) ----
  char* p = (char*)d_ws;
  auto carve = [&](size_t bytes) -> char* {
    char* r = p; p += (bytes + 255) & ~(size_t)255; return r;
  };
  unsigned short* Wgvd4 = (unsigned short*)carve((size_t)4 * DDIM * DDIM * 2);
  unsigned short* WguT  = (unsigned short*)carve((size_t)2 * FDIM * DDIM * 2);
  unsigned short* WoutT = (unsigned short*)carve((size_t)DDIM * FDIM * 2);
  float* bias = (float*)carve(3 * DDIM * 4);
  const size_t fixed_used = (size_t)(p - (char*)d_ws);

  const size_t xn_b  = (size_t)SS * DDIM * 2;
  const size_t ax_b  = (size_t)SS * 2 * DDIM * 2;          // fp16 (om, xs)
  const size_t tact_b = (size_t)SS * FDIM * 2;             // bf16 FFN activations
  const size_t shr_b = (ax_b > tact_b) ? ax_b : tact_b;    // union buffer
  const size_t ach_b = (size_t)NCH * DDIM * 4;
  const size_t per_batch = xn_b + shr_b + 3 * ach_b + 2048;
  long long avail = (long long)ws_size - (long long)fixed_used;
  int nb = (avail > 0) ? (int)(avail / (long long)per_batch) : 1;
  if (nb < 1) nb = 1;
  if (nb > BB) nb = BB;

  unsigned short* xn = (unsigned short*)carve((size_t)nb * xn_b);
  char* shr = carve((size_t)nb * shr_b);
  __half* ax = (__half*)shr;
  unsigned short* tact = (unsigned short*)shr;      // aliases ax (dead after scan)
  float* Ac   = (float*)carve((size_t)nb * ach_b);
  float* Hc   = (float*)carve((size_t)nb * ach_b);
  float* Hpre = (float*)carve((size_t)nb * ach_b);

  // ---- pack weights once + bias ----
  pack_w<<<dim3(16, 16), 256, 0, stream>>>(Wg,  Wgvd4, DDIM, DDIM, 3, 0);
  pack_w<<<dim3(16, 16), 256, 0, stream>>>(Wv,  Wgvd4, DDIM, DDIM, 4, 0);
  pack_w<<<dim3(16, 16), 256, 0, stream>>>(Wd,  Wgvd4, DDIM, DDIM, 5, 0);
  pack_w<<<dim3(48, 16), 256, 0, stream>>>(Wga, WguT,  FDIM, DDIM, 1, 0);
  pack_w<<<dim3(48, 16), 256, 0, stream>>>(Wup, WguT,  FDIM, DDIM, 2, 0);
  pack_w<<<dim3(16, 48), 256, 0, stream>>>(Wo,  WoutT, DDIM, FDIM, 0, 0);
  pack_bias<<<4, 256, 0, stream>>>(bg, bv, bd, bias);

  // ---- per-batch-group pipeline ----
  for (int b0 = 0; b0 < BB; b0 += nb) {
    const int n  = (BB - b0 < nb) ? (BB - b0) : nb;
    const int Mg = n * SS;
    const float* xg   = x   + (size_t)b0 * SS * DDIM;
    float*       outg = out + (size_t)b0 * SS * DDIM;

    // rmsnorm #1 -> xn (bf16)
    rmsnorm_kernel<<<Mg, 256, 0, stream>>>(xg, w_rms_mix, xn);

    // mixer GEMM (16x16, pad MFMAs skipped): epilogue -> (om, xs) fp16
    gemm_mix<<<dim3(4 * DDIM / 256, Mg / 256), 512, 0, stream>>>(
        xn, Wgvd4, 4 * DDIM, DDIM, bias, ax);

    // chunked scan -> outg = x + h
    scan_phase1<<<dim3(DDIM / 256, NCH, n), 256, 0, stream>>>(ax, Ac, Hc);
    scan_phase2<<<(n * DDIM) / 256, 256, 0, stream>>>(Ac, Hc, Hpre);
    scan_phase3<<<dim3(DDIM / 256, NCH, n), 256, 0, stream>>>(ax, xg, Hpre, outg);

    // rmsnorm #2 -> yn (bf16, reuse xn)
    rmsnorm_kernel<<<Mg, 256, 0, stream>>>(outg, w_rms_ffn, xn);

    // FFN1 (32x32): tact = silu(yn@Wgate) * (yn@Wup)  (bf16, fused epilogue)
    gemm256w<1><<<dim3(2 * FDIM / 256, Mg / 256), 512, 0, stream>>>(
        xn, WguT, 2 * FDIM, DDIM, nullptr, nullptr, tact);

    // FFN2 (32x32): outg = tact @ Wout + outg(resid)
    gemm256w<2><<<dim3(DDIM / 256, Mg / 256), 512, 0, stream>>>(
        tact, WoutT, DDIM, FDIM, outg, outg, nullptr);
  }
}

// Round 9
// 997.504 us; speedup vs baseline: 1.4022x; 1.0288x over previous
//
#include <hip/hip_runtime.h>
#include <hip/hip_fp16.h>

#define BB 8
#define SS 4096
#define DDIM 1024
#define FDIM 3072
#define CHUNK 128
#define NCH (SS/CHUNK)      // 32 chunks per sequence

typedef __attribute__((ext_vector_type(8))) __bf16 bf16x8;
typedef __attribute__((ext_vector_type(4))) float f32x4;

__device__ __forceinline__ unsigned short f2bf(float f) {
  unsigned int u = __builtin_bit_cast(unsigned int, f);
  u += 0x7FFFu + ((u >> 16) & 1u);          // round-to-nearest-even
  return (unsigned short)(u >> 16);
}
__device__ __forceinline__ float sigmoid_(float x) { return 1.0f / (1.0f + __expf(-x)); }
__device__ __forceinline__ float tanh_(float x) {
  float xc = fminf(fmaxf(x, -15.0f), 15.0f);
  float e = __expf(2.0f * xc);
  return (e - 1.0f) / (e + 1.0f);
}

// ---------------- weight transpose + bf16 pack ----------------
__global__ __launch_bounds__(256)
void pack_w(const float* __restrict__ src, unsigned short* __restrict__ dst,
            int Csrc, int Kd, int mode, int rowoff)
{
  __shared__ float tile[64][65];
  const int k0 = blockIdx.y << 6;
  const int c0 = blockIdx.x << 6;
  const int t  = threadIdx.x;
  const int tc = t & 63;
  const int tr = t >> 6;
#pragma unroll
  for (int j = 0; j < 16; j++) {
    int r = (j << 2) + tr;
    tile[r][tc] = src[(size_t)(k0 + r) * Csrc + c0 + tc];
  }
  __syncthreads();
#pragma unroll
  for (int j = 0; j < 16; j++) {
    int c  = (j << 2) + tr;
    int gc = c0 + c;
    int np;
    if (mode == 0)      np = gc + rowoff;
    else if (mode == 1) np = ((gc >> 5) << 6) + (gc & 31);
    else if (mode == 2) np = ((gc >> 5) << 6) + 32 + (gc & 31);
    else                np = ((gc >> 4) << 6) + ((mode - 3) << 4) + (gc & 15);
    dst[(size_t)np * Kd + k0 + tc] = f2bf(tile[tc][c]);
    if (mode == 5) dst[(size_t)(np + 16) * Kd + k0 + tc] = 0;   // zero plane 3
  }
}

__global__ void pack_bias(const float* __restrict__ bg, const float* __restrict__ bv,
                          const float* __restrict__ bd, float* __restrict__ bias)
{
  int i = blockIdx.x * 256 + threadIdx.x;
  if (i < DDIM) { bias[i] = bg[i]; bias[i + DDIM] = bv[i]; bias[i + 2 * DDIM] = bd[i]; }
}

// ---------------- RMSNorm: fp32 in -> bf16 out ----------------
__global__ __launch_bounds__(256)
void rmsnorm_kernel(const float* __restrict__ x, const float* __restrict__ w,
                    unsigned short* __restrict__ out)
{
  const int row = blockIdx.x;
  const int t = threadIdx.x;
  const float4 v = reinterpret_cast<const float4*>(x + (size_t)row * DDIM)[t];
  float ss = v.x * v.x + v.y * v.y + v.z * v.z + v.w * v.w;
#pragma unroll
  for (int o = 32; o > 0; o >>= 1) ss += __shfl_down(ss, o);
  __shared__ float wsum[4];
  if ((t & 63) == 0) wsum[t >> 6] = ss;
  __syncthreads();
  float tot = wsum[0] + wsum[1] + wsum[2] + wsum[3];
  const float rms = rsqrtf(tot * (1.0f / DDIM) + 1e-6f);
  const float4 wv = reinterpret_cast<const float4*>(w)[t];
  ushort4 o4;
  o4.x = f2bf(v.x * rms * wv.x);
  o4.y = f2bf(v.y * rms * wv.y);
  o4.z = f2bf(v.z * rms * wv.z);
  o4.w = f2bf(v.w * rms * wv.w);
  reinterpret_cast<ushort4*>(out + (size_t)row * DDIM)[t] = o4;
}

// ---------------- 256x256 8-phase pipelined bf16 MFMA GEMM (16x16) ----------------
// Proven R6 structure: per phase [early ds_read] -> lgkm wait -> MFMA ->
// [late ds_read] -> stage -> [vmcnt(6) at ph3/ph7] -> barrier; half-woven
// af reloads in ph2/4/6/8. XOR swizzle byte^=(row&7)<<4 via pre-swizzled
// global source; B rows nh-major. 0 bank conflicts (16-row x 4-kchunk reads).

#define SB0 __builtin_amdgcn_sched_barrier(0)
#define BAR __builtin_amdgcn_s_barrier()
#define PRIO1 __builtin_amdgcn_s_setprio(1)
#define PRIO0 __builtin_amdgcn_s_setprio(0)
#define WAITL4 do { asm volatile("s_waitcnt lgkmcnt(4)" ::: "memory"); SB0; } while (0)
#define WAITL0 do { asm volatile("s_waitcnt lgkmcnt(0)" ::: "memory"); SB0; } while (0)
#define WAITV6 do { asm volatile("s_waitcnt vmcnt(6)" ::: "memory"); } while (0)
#define WAITV0 do { asm volatile("s_waitcnt vmcnt(0)" ::: "memory"); } while (0)

#define DSR(D, A, O) asm volatile("ds_read_b128 %0, %1 offset:" O : "=v"(D) : "v"(A))
#define RD_BF(B, O0, O1) do { \
  DSR(B[0][0], bB0, O0); DSR(B[0][1], bB1, O0); \
  DSR(B[1][0], bB0, O1); DSR(B[1][1], bB1, O1); } while (0)

template<int MH, int NH, bool SKIP1>
__device__ __forceinline__ void mfma_quad(f32x4 (&acc)[8][4], const bf16x8 (&af)[4][2],
                                          const bf16x8 (&bf)[2][2])
{
#pragma unroll
  for (int mf = 0; mf < 4; mf++)
#pragma unroll
    for (int nf = 0; nf < (SKIP1 ? 1 : 2); nf++)
#pragma unroll
      for (int kk = 0; kk < 2; kk++)
        acc[MH * 4 + mf][NH * 2 + nf] = __builtin_amdgcn_mfma_f32_16x16x32_bf16(
            af[mf][kk], bf[nf][kk], acc[MH * 4 + mf][NH * 2 + nf], 0, 0, 0);
}
// half-quad: H=0 -> mf {0,1}; H=1 -> mf {2,3}
template<int MH, int NH, int H, bool SKIP1>
__device__ __forceinline__ void mfma_quad_h(f32x4 (&acc)[8][4], const bf16x8 (&af)[4][2],
                                            const bf16x8 (&bf)[2][2])
{
#pragma unroll
  for (int mf = H * 2; mf < H * 2 + 2; mf++)
#pragma unroll
    for (int nf = 0; nf < (SKIP1 ? 1 : 2); nf++)
#pragma unroll
      for (int kk = 0; kk < 2; kk++)
        acc[MH * 4 + mf][NH * 2 + nf] = __builtin_amdgcn_mfma_f32_16x16x32_bf16(
            af[mf][kk], bf[nf][kk], acc[MH * 4 + mf][NH * 2 + nf], 0, 0, 0);
}

// shared GEMM body as a macro-free template via EPIlogue functor pattern:
// EPI 1: swiglu bf16 out; EPI 2: +resid fp32 out (R6 verbatim)
template<int EPI>
__global__ __launch_bounds__(512, 2)
void gemm256(const unsigned short* __restrict__ A,
             const unsigned short* __restrict__ Bt,
             int Np, int K,
             const float* __restrict__ bias,
             const float* __restrict__ resid,
             float* __restrict__ outf,
             unsigned short* __restrict__ outh)
{
  __shared__ __align__(16) unsigned short ldsA[2][256 * 64];
  __shared__ __align__(16) unsigned short ldsB[2][256 * 64];
  const int tid = threadIdx.x, wid = tid >> 6, lane = tid & 63;
  constexpr bool SK = false;

  const int gx = gridDim.x;
  const int lin = blockIdx.y * gx + blockIdx.x;
  const int cpx = (gx * gridDim.y) >> 3;
  const int swz = (lin & 7) * cpx + (lin >> 3);
  const int bx = swz % gx, by = swz / gx;
  const int m0 = by << 8, n0 = bx << 8;
  const int wr = wid >> 2, wc = wid & 3;

  f32x4 acc[8][4];
  const f32x4 zero = {0.f, 0.f, 0.f, 0.f};
#pragma unroll
  for (int a = 0; a < 8; a++)
#pragma unroll
    for (int j = 0; j < 4; j++) acc[a][j] = zero;

  const int swzk = (((tid & 7) ^ ((tid >> 3) & 7)) << 3);
  auto stA = [&](int p, int u, int t) {
#pragma unroll
    for (int r = 0; r < 2; r++) {
      const int lrow0 = (r << 7) + (u << 6);
      const int grow = m0 + lrow0 + (tid >> 3);
      const unsigned short* src = A + (size_t)grow * K + (t << 6) + swzk;
      unsigned short* dst = &ldsA[p][lrow0 << 6] + (wid << 9);
      __builtin_amdgcn_global_load_lds(
          (const __attribute__((address_space(1))) void*)src,
          (__attribute__((address_space(3))) void*)dst, 16, 0, 0);
    }
  };
  auto stB = [&](int p, int u, int t) {
#pragma unroll
    for (int r = 0; r < 2; r++) {
      const int j = (r << 6) + (tid >> 3);
      const int lrow0 = (u << 7) + (r << 6);
      const int gcol = n0 + ((j >> 5) << 6) + (u << 5) + (j & 31);
      const unsigned short* src = Bt + (size_t)gcol * K + (t << 6) + swzk;
      unsigned short* dst = &ldsB[p][lrow0 << 6] + (wid << 9);
      __builtin_amdgcn_global_load_lds(
          (const __attribute__((address_space(1))) void*)src,
          (__attribute__((address_space(3))) void*)dst, 16, 0, 0);
    }
  };

  const unsigned laneR = (unsigned)((lane & 15) << 7);
  const unsigned sw    = (unsigned)((lane & 7) << 4);
  const unsigned k0b   = (unsigned)((lane >> 4) << 4);
  const unsigned baseA = (unsigned)(uintptr_t)&ldsA[0][0] + ((unsigned)wr << 14);
  const unsigned baseB = (unsigned)(uintptr_t)&ldsB[0][0] + ((unsigned)wc << 12);
  const unsigned aA0 = baseA + laneR + (k0b ^ sw);
  const unsigned aA1 = baseA + laneR + ((64u + k0b) ^ sw);
  const unsigned bB0 = baseB + laneR + (k0b ^ sw);
  const unsigned bB1 = baseB + laneR + ((64u + k0b) ^ sw);

  bf16x8 af[4][2];
  bf16x8 bf0[2][2];
  bf16x8 bf1[2][2];

  const int NITER = (K >> 6) >> 1;

  stB(0, 0, 0); stA(0, 0, 0); stB(0, 1, 0); stA(0, 1, 0);
  stB(1, 0, 1); stA(1, 0, 1); stB(1, 1, 1); stA(1, 1, 1);
  asm volatile("s_waitcnt vmcnt(8)" ::: "memory");
  BAR; SB0;
  DSR(af[0][0], aA0, "0");    DSR(af[0][1], aA1, "0");
  DSR(af[1][0], aA0, "2048"); DSR(af[1][1], aA1, "2048");
  DSR(af[2][0], aA0, "4096"); DSR(af[2][1], aA1, "4096");
  DSR(af[3][0], aA0, "6144"); DSR(af[3][1], aA1, "6144");
  DSR(bf0[0][0], bB0, "0");    DSR(bf0[0][1], bB1, "0");
  DSR(bf0[1][0], bB0, "2048"); DSR(bf0[1][1], bB1, "2048");

  for (int i = 0; i < NITER; i++) {
    const int t2 = i << 1;
    const bool more = (i + 1 < NITER);

    RD_BF(bf1, "16384", "18432");
    WAITL4;
    PRIO1; mfma_quad<0, 0, false>(acc, af, bf0); PRIO0; SB0;
    if (more) stB(0, 0, t2 + 2);
    BAR;

    WAITL0;
    PRIO1; mfma_quad_h<0, 1, 0, SK>(acc, af, bf1); SB0;
    DSR(af[0][0], aA0, "8192");  DSR(af[0][1], aA1, "8192");
    DSR(af[1][0], aA0, "10240"); DSR(af[1][1], aA1, "10240"); SB0;
    mfma_quad_h<0, 1, 1, SK>(acc, af, bf1); PRIO0; SB0;
    DSR(af[2][0], aA0, "12288"); DSR(af[2][1], aA1, "12288");
    DSR(af[3][0], aA0, "14336"); DSR(af[3][1], aA1, "14336");
    if (more) stA(0, 0, t2 + 2);
    BAR;

    WAITL0;
    PRIO1; mfma_quad<1, 0, false>(acc, af, bf0); PRIO0; SB0;
    if (more) stB(0, 1, t2 + 2);
    if (more) WAITV6; else WAITV0;
    BAR;

    RD_BF(bf0, "32768", "34816");
    PRIO1; mfma_quad_h<1, 1, 0, SK>(acc, af, bf1); SB0;
    DSR(af[0][0], aA0, "32768"); DSR(af[0][1], aA1, "32768");
    DSR(af[1][0], aA0, "34816"); DSR(af[1][1], aA1, "34816"); SB0;
    mfma_quad_h<1, 1, 1, SK>(acc, af, bf1); PRIO0; SB0;
    DSR(af[2][0], aA0, "36864"); DSR(af[2][1], aA1, "36864");
    DSR(af[3][0], aA0, "38912"); DSR(af[3][1], aA1, "38912");
    if (more) stA(0, 1, t2 + 2);
    BAR;

    RD_BF(bf1, "49152", "51200");
    WAITL4;
    PRIO1; mfma_quad<0, 0, false>(acc, af, bf0); PRIO0; SB0;
    if (more) stB(1, 0, t2 + 3);
    BAR;

    WAITL0;
    PRIO1; mfma_quad_h<0, 1, 0, SK>(acc, af, bf1); SB0;
    DSR(af[0][0], aA0, "40960"); DSR(af[0][1], aA1, "40960");
    DSR(af[1][0], aA0, "43008"); DSR(af[1][1], aA1, "43008"); SB0;
    mfma_quad_h<0, 1, 1, SK>(acc, af, bf1); PRIO0; SB0;
    DSR(af[2][0], aA0, "45056"); DSR(af[2][1], aA1, "45056");
    DSR(af[3][0], aA0, "47104"); DSR(af[3][1], aA1, "47104");
    if (more) stA(1, 0, t2 + 3);
    BAR;

    WAITL0;
    PRIO1; mfma_quad<1, 0, false>(acc, af, bf0); PRIO0; SB0;
    if (more) stB(1, 1, t2 + 3);
    if (more) WAITV6;
    BAR;

    RD_BF(bf0, "0", "2048");
    PRIO1; mfma_quad_h<1, 1, 0, SK>(acc, af, bf1); SB0;
    DSR(af[0][0], aA0, "0");    DSR(af[0][1], aA1, "0");
    DSR(af[1][0], aA0, "2048"); DSR(af[1][1], aA1, "2048"); SB0;
    mfma_quad_h<1, 1, 1, SK>(acc, af, bf1); PRIO0; SB0;
    DSR(af[2][0], aA0, "4096"); DSR(af[2][1], aA1, "4096");
    DSR(af[3][0], aA0, "6144"); DSR(af[3][1], aA1, "6144");
    if (more) stA(1, 1, t2 + 3);
    BAR;
  }
  asm volatile("s_waitcnt lgkmcnt(0)" ::: "memory"); SB0;

  const int lcol = lane & 15;
  const int rgrp = (lane >> 4) << 2;
  if (EPI == 1) {
    const int tN = Np >> 1;
#pragma unroll
    for (int a = 0; a < 8; a++)
#pragma unroll
      for (int j = 0; j < 2; j++) {
        const int tcol = (n0 >> 1) + (wc << 5) + (j << 4) + lcol;
#pragma unroll
        for (int rg = 0; rg < 4; rg++) {
          const int row = m0 + (wr << 7) + (a << 4) + rgrp + rg;
          const float g = acc[a][j][rg];
          const float u = acc[a][j + 2][rg];
          const float s = g / (1.0f + __expf(-g));      // silu
          outh[(size_t)row * tN + tcol] = f2bf(s * u);
        }
      }
  } else {
#pragma unroll
    for (int a = 0; a < 8; a++)
#pragma unroll
      for (int j = 0; j < 4; j++) {
        const int col = n0 + (wc << 6) + (j << 4) + lcol;
#pragma unroll
        for (int rg = 0; rg < 4; rg++) {
          const int row = m0 + (wr << 7) + (a << 4) + rgrp + rg;
          outf[(size_t)row * Np + col] = acc[a][j][rg] + resid[(size_t)row * Np + col];
        }
      }
  }
}

// ---------------- mixer GEMM: same core, SK=true, fp16 (om,xs) epilogue ----------------
__global__ __launch_bounds__(512, 2)
void gemm_mix(const unsigned short* __restrict__ A,
              const unsigned short* __restrict__ Bt,
              int Np, int K,
              const float* __restrict__ bias,
              __half* __restrict__ axh)
{
  __shared__ __align__(16) unsigned short ldsA[2][256 * 64];
  __shared__ __align__(16) unsigned short ldsB[2][256 * 64];
  const int tid = threadIdx.x, wid = tid >> 6, lane = tid & 63;
  constexpr bool SK = true;   // skip pad plane

  const int gx = gridDim.x;
  const int lin = blockIdx.y * gx + blockIdx.x;
  const int cpx = (gx * gridDim.y) >> 3;
  const int swz = (lin & 7) * cpx + (lin >> 3);
  const int bx = swz % gx, by = swz / gx;
  const int m0 = by << 8, n0 = bx << 8;
  const int wr = wid >> 2, wc = wid & 3;

  f32x4 acc[8][4];
  const f32x4 zero = {0.f, 0.f, 0.f, 0.f};
#pragma unroll
  for (int a = 0; a < 8; a++)
#pragma unroll
    for (int j = 0; j < 4; j++) acc[a][j] = zero;

  const int swzk = (((tid & 7) ^ ((tid >> 3) & 7)) << 3);
  auto stA = [&](int p, int u, int t) {
#pragma unroll
    for (int r = 0; r < 2; r++) {
      const int lrow0 = (r << 7) + (u << 6);
      const int grow = m0 + lrow0 + (tid >> 3);
      const unsigned short* src = A + (size_t)grow * K + (t << 6) + swzk;
      unsigned short* dst = &ldsA[p][lrow0 << 6] + (wid << 9);
      __builtin_amdgcn_global_load_lds(
          (const __attribute__((address_space(1))) void*)src,
          (__attribute__((address_space(3))) void*)dst, 16, 0, 0);
    }
  };
  auto stB = [&](int p, int u, int t) {
#pragma unroll
    for (int r = 0; r < 2; r++) {
      const int j = (r << 6) + (tid >> 3);
      const int lrow0 = (u << 7) + (r << 6);
      const int gcol = n0 + ((j >> 5) << 6) + (u << 5) + (j & 31);
      const unsigned short* src = Bt + (size_t)gcol * K + (t << 6) + swzk;
      unsigned short* dst = &ldsB[p][lrow0 << 6] + (wid << 9);
      __builtin_amdgcn_global_load_lds(
          (const __attribute__((address_space(1))) void*)src,
          (__attribute__((address_space(3))) void*)dst, 16, 0, 0);
    }
  };

  const unsigned laneR = (unsigned)((lane & 15) << 7);
  const unsigned sw    = (unsigned)((lane & 7) << 4);
  const unsigned k0b   = (unsigned)((lane >> 4) << 4);
  const unsigned baseA = (unsigned)(uintptr_t)&ldsA[0][0] + ((unsigned)wr << 14);
  const unsigned baseB = (unsigned)(uintptr_t)&ldsB[0][0] + ((unsigned)wc << 12);
  const unsigned aA0 = baseA + laneR + (k0b ^ sw);
  const unsigned aA1 = baseA + laneR + ((64u + k0b) ^ sw);
  const unsigned bB0 = baseB + laneR + (k0b ^ sw);
  const unsigned bB1 = baseB + laneR + ((64u + k0b) ^ sw);

  bf16x8 af[4][2];
  bf16x8 bf0[2][2];
  bf16x8 bf1[2][2];

  const int NITER = (K >> 6) >> 1;

  stB(0, 0, 0); stA(0, 0, 0); stB(0, 1, 0); stA(0, 1, 0);
  stB(1, 0, 1); stA(1, 0, 1); stB(1, 1, 1); stA(1, 1, 1);
  asm volatile("s_waitcnt vmcnt(8)" ::: "memory");
  BAR; SB0;
  DSR(af[0][0], aA0, "0");    DSR(af[0][1], aA1, "0");
  DSR(af[1][0], aA0, "2048"); DSR(af[1][1], aA1, "2048");
  DSR(af[2][0], aA0, "4096"); DSR(af[2][1], aA1, "4096");
  DSR(af[3][0], aA0, "6144"); DSR(af[3][1], aA1, "6144");
  DSR(bf0[0][0], bB0, "0");    DSR(bf0[0][1], bB1, "0");
  DSR(bf0[1][0], bB0, "2048"); DSR(bf0[1][1], bB1, "2048");

  for (int i = 0; i < NITER; i++) {
    const int t2 = i << 1;
    const bool more = (i + 1 < NITER);

    RD_BF(bf1, "16384", "18432");
    WAITL4;
    PRIO1; mfma_quad<0, 0, false>(acc, af, bf0); PRIO0; SB0;
    if (more) stB(0, 0, t2 + 2);
    BAR;

    WAITL0;
    PRIO1; mfma_quad_h<0, 1, 0, SK>(acc, af, bf1); SB0;
    DSR(af[0][0], aA0, "8192");  DSR(af[0][1], aA1, "8192");
    DSR(af[1][0], aA0, "10240"); DSR(af[1][1], aA1, "10240"); SB0;
    mfma_quad_h<0, 1, 1, SK>(acc, af, bf1); PRIO0; SB0;
    DSR(af[2][0], aA0, "12288"); DSR(af[2][1], aA1, "12288");
    DSR(af[3][0], aA0, "14336"); DSR(af[3][1], aA1, "14336");
    if (more) stA(0, 0, t2 + 2);
    BAR;

    WAITL0;
    PRIO1; mfma_quad<1, 0, false>(acc, af, bf0); PRIO0; SB0;
    if (more) stB(0, 1, t2 + 2);
    if (more) WAITV6; else WAITV0;
    BAR;

    RD_BF(bf0, "32768", "34816");
    PRIO1; mfma_quad_h<1, 1, 0, SK>(acc, af, bf1); SB0;
    DSR(af[0][0], aA0, "32768"); DSR(af[0][1], aA1, "32768");
    DSR(af[1][0], aA0, "34816"); DSR(af[1][1], aA1, "34816"); SB0;
    mfma_quad_h<1, 1, 1, SK>(acc, af, bf1); PRIO0; SB0;
    DSR(af[2][0], aA0, "36864"); DSR(af[2][1], aA1, "36864");
    DSR(af[3][0], aA0, "38912"); DSR(af[3][1], aA1, "38912");
    if (more) stA(0, 1, t2 + 2);
    BAR;

    RD_BF(bf1, "49152", "51200");
    WAITL4;
    PRIO1; mfma_quad<0, 0, false>(acc, af, bf0); PRIO0; SB0;
    if (more) stB(1, 0, t2 + 3);
    BAR;

    WAITL0;
    PRIO1; mfma_quad_h<0, 1, 0, SK>(acc, af, bf1); SB0;
    DSR(af[0][0], aA0, "40960"); DSR(af[0][1], aA1, "40960");
    DSR(af[1][0], aA0, "43008"); DSR(af[1][1], aA1, "43008"); SB0;
    mfma_quad_h<0, 1, 1, SK>(acc, af, bf1); PRIO0; SB0;
    DSR(af[2][0], aA0, "45056"); DSR(af[2][1], aA1, "45056");
    DSR(af[3][0], aA0, "47104"); DSR(af[3][1], aA1, "47104");
    if (more) stA(1, 0, t2 + 3);
    BAR;

    WAITL0;
    PRIO1; mfma_quad<1, 0, false>(acc, af, bf0); PRIO0; SB0;
    if (more) stB(1, 1, t2 + 3);
    if (more) WAITV6;
    BAR;

    RD_BF(bf0, "0", "2048");
    PRIO1; mfma_quad_h<1, 1, 0, SK>(acc, af, bf1); SB0;
    DSR(af[0][0], aA0, "0");    DSR(af[0][1], aA1, "0");
    DSR(af[1][0], aA0, "2048"); DSR(af[1][1], aA1, "2048"); SB0;
    mfma_quad_h<1, 1, 1, SK>(acc, af, bf1); PRIO0; SB0;
    DSR(af[2][0], aA0, "4096"); DSR(af[2][1], aA1, "4096");
    DSR(af[3][0], aA0, "6144"); DSR(af[3][1], aA1, "6144");
    if (more) stA(1, 1, t2 + 3);
    BAR;
  }
  asm volatile("s_waitcnt lgkmcnt(0)" ::: "memory"); SB0;

  // epilogue: (om = 1-a, xs) fp16
  const int lcol = lane & 15;
  const int rgrp = (lane >> 4) << 2;
  const int ch = (n0 >> 2) + (wc << 4) + lcol;        // channel 0..1023
  const float bgv = bias[ch], bvv = bias[ch + DDIM], bdv = bias[ch + 2 * DDIM];
#pragma unroll
  for (int a = 0; a < 8; a++)
#pragma unroll
    for (int rg = 0; rg < 4; rg++) {
      const int row = m0 + (wr << 7) + (a << 4) + rgrp + rg;
      const float g  = acc[a][0][rg] + bgv;
      const float v  = acc[a][1][rg] + bvv;
      const float dd = acc[a][2][rg] + bdv;
      const float om = 0.998f * sigmoid_(-dd) + 0.001f;   // 1 - a
      const float xs = sigmoid_(g) * tanh_(v);
      __half* o = axh + (size_t)row * (2 * DDIM);
      o[ch] = __float2half_rn(om);
      o[ch + DDIM] = __float2half_rn(xs);
    }
}

// ---------------- chunked linear scan over fp16 (om=1-a, xs) ----------------
__global__ __launch_bounds__(256)
void scan_phase1(const __half* __restrict__ ax, float* __restrict__ Ac, float* __restrict__ Hc)
{
  const int d = blockIdx.x * 256 + threadIdx.x;
  const int ch = blockIdx.y;
  const int b = blockIdx.z;
  size_t base = ((size_t)b * SS + (size_t)ch * CHUNK) * (2 * DDIM) + d;
  float Aprod = 1.0f, H = 0.0f;
  for (int s = 0; s < CHUNK; s++) {
    const float a  = 1.0f - __half2float(ax[base]);
    const float xs = __half2float(ax[base + DDIM]);
    H = a * H + xs;
    Aprod *= a;
    base += 2 * DDIM;
  }
  const int idx = (b * NCH + ch) * DDIM + d;
  Ac[idx] = Aprod;
  Hc[idx] = H;
}

__global__ void scan_phase2(const float* __restrict__ Ac, const float* __restrict__ Hc,
                            float* __restrict__ Hpre)
{
  const int idx = blockIdx.x * 256 + threadIdx.x;
  const int b = idx >> 10, d = idx & (DDIM - 1);
  float h = 0.0f;
  for (int c = 0; c < NCH; c++) {
    const int i = (b * NCH + c) * DDIM + d;
    Hpre[i] = h;
    h = Ac[i] * h + Hc[i];
  }
}

__global__ __launch_bounds__(256)
void scan_phase3(const __half* __restrict__ ax, const float* __restrict__ x,
                 const float* __restrict__ Hpre, float* __restrict__ xres)
{
  const int d = blockIdx.x * 256 + threadIdx.x;
  const int ch = blockIdx.y;
  const int b = blockIdx.z;
  float H = Hpre[(b * NCH + ch) * DDIM + d];
  const size_t mbase = (size_t)b * SS + (size_t)ch * CHUNK;
  size_t base  = mbase * (2 * DDIM) + d;
  size_t xbase = mbase * DDIM + d;
  for (int s = 0; s < CHUNK; s++) {
    const float a  = 1.0f - __half2float(ax[base]);
    const float xs = __half2float(ax[base + DDIM]);
    H = a * H + xs;
    xres[xbase] = x[xbase] + H;
    base += 2 * DDIM;
    xbase += DDIM;
  }
}

// ---------------- launch ----------------
extern "C" void kernel_launch(void* const* d_in, const int* in_sizes, int n_in,
                              void* d_out, int out_size, void* d_ws, size_t ws_size,
                              hipStream_t stream)
{
  const float* x         = (const float*)d_in[0];
  const float* w_rms_mix = (const float*)d_in[1];
  const float* w_rms_ffn = (const float*)d_in[2];
  const float* Wg  = (const float*)d_in[3];
  const float* bg  = (const float*)d_in[4];
  const float* Wv  = (const float*)d_in[5];
  const float* bv  = (const float*)d_in[6];
  const float* Wd  = (const float*)d_in[7];
  const float* bd  = (const float*)d_in[8];
  const float* Wga = (const float*)d_in[9];
  const float* Wup = (const float*)d_in[10];
  const float* Wo  = (const float*)d_in[11];
  float* out = (float*)d_out;

  // ---- workspace carve (ws-size adaptive) ----
  char* p = (char*)d_ws;
  auto carve = [&](size_t bytes) -> char* {
    char* r = p; p += (bytes + 255) & ~(size_t)255; return r;
  };
  unsigned short* Wgvd4 = (unsigned short*)carve((size_t)4 * DDIM * DDIM * 2);
  unsigned short* WguT  = (unsigned short*)carve((size_t)2 * FDIM * DDIM * 2);
  unsigned short* WoutT = (unsigned short*)carve((size_t)DDIM * FDIM * 2);
  float* bias = (float*)carve(3 * DDIM * 4);
  const size_t fixed_used = (size_t)(p - (char*)d_ws);

  const size_t xn_b  = (size_t)SS * DDIM * 2;
  const size_t ax_b  = (size_t)SS * 2 * DDIM * 2;          // fp16 (om, xs)
  const size_t tact_b = (size_t)SS * FDIM * 2;             // bf16 FFN activations
  const size_t shr_b = (ax_b > tact_b) ? ax_b : tact_b;    // union buffer
  const size_t ach_b = (size_t)NCH * DDIM * 4;
  const size_t per_batch = xn_b + shr_b + 3 * ach_b + 2048;
  long long avail = (long long)ws_size - (long long)fixed_used;
  int nb = (avail > 0) ? (int)(avail / (long long)per_batch) : 1;
  if (nb < 1) nb = 1;
  if (nb > BB) nb = BB;

  unsigned short* xn = (unsigned short*)carve((size_t)nb * xn_b);
  char* shr = carve((size_t)nb * shr_b);
  __half* ax = (__half*)shr;
  unsigned short* tact = (unsigned short*)shr;      // aliases ax (dead after scan)
  float* Ac   = (float*)carve((size_t)nb * ach_b);
  float* Hc   = (float*)carve((size_t)nb * ach_b);
  float* Hpre = (float*)carve((size_t)nb * ach_b);

  // ---- pack weights once + bias ----
  pack_w<<<dim3(16, 16), 256, 0, stream>>>(Wg,  Wgvd4, DDIM, DDIM, 3, 0);
  pack_w<<<dim3(16, 16), 256, 0, stream>>>(Wv,  Wgvd4, DDIM, DDIM, 4, 0);
  pack_w<<<dim3(16, 16), 256, 0, stream>>>(Wd,  Wgvd4, DDIM, DDIM, 5, 0);
  pack_w<<<dim3(48, 16), 256, 0, stream>>>(Wga, WguT,  FDIM, DDIM, 1, 0);
  pack_w<<<dim3(48, 16), 256, 0, stream>>>(Wup, WguT,  FDIM, DDIM, 2, 0);
  pack_w<<<dim3(16, 48), 256, 0, stream>>>(Wo,  WoutT, DDIM, FDIM, 0, 0);
  pack_bias<<<4, 256, 0, stream>>>(bg, bv, bd, bias);

  // ---- per-batch-group pipeline ----
  for (int b0 = 0; b0 < BB; b0 += nb) {
    const int n  = (BB - b0 < nb) ? (BB - b0) : nb;
    const int Mg = n * SS;
    const float* xg   = x   + (size_t)b0 * SS * DDIM;
    float*       outg = out + (size_t)b0 * SS * DDIM;

    // rmsnorm #1 -> xn (bf16)
    rmsnorm_kernel<<<Mg, 256, 0, stream>>>(xg, w_rms_mix, xn);

    // mixer GEMM (16x16, pad MFMAs skipped): epilogue -> (om, xs) fp16
    gemm_mix<<<dim3(4 * DDIM / 256, Mg / 256), 512, 0, stream>>>(
        xn, Wgvd4, 4 * DDIM, DDIM, bias, ax);

    // chunked scan -> outg = x + h
    scan_phase1<<<dim3(DDIM / 256, NCH, n), 256, 0, stream>>>(ax, Ac, Hc);
    scan_phase2<<<(n * DDIM) / 256, 256, 0, stream>>>(Ac, Hc, Hpre);
    scan_phase3<<<dim3(DDIM / 256, NCH, n), 256, 0, stream>>>(ax, xg, Hpre, outg);

    // rmsnorm #2 -> yn (bf16, reuse xn)
    rmsnorm_kernel<<<Mg, 256, 0, stream>>>(outg, w_rms_ffn, xn);

    // FFN1 (16x16): tact = silu(yn@Wgate) * (yn@Wup)  (bf16, fused epilogue)
    gemm256<1><<<dim3(2 * FDIM / 256, Mg / 256), 512, 0, stream>>>(
        xn, WguT, 2 * FDIM, DDIM, nullptr, nullptr, nullptr, tact);

    // FFN2 (16x16): outg = tact @ Wout + outg(resid)
    gemm256<2><<<dim3(DDIM / 256, Mg / 256), 512, 0, stream>>>(
        tact, WoutT, DDIM, FDIM, nullptr, outg, outg, nullptr);
  }
}